// Round 1
// baseline (458.242 us; speedup 1.0000x reference)
//
#include <hip/hip_runtime.h>
#include <hip/hip_bf16.h>
#include <cstdint>
#include <cstddef>

#define NN 100000
#define NE 1600000
#define KD 256
#define OD 128

typedef __attribute__((ext_vector_type(8))) __bf16 bf16x8;
typedef __attribute__((ext_vector_type(4))) float f32x4;
typedef __attribute__((ext_vector_type(8))) unsigned short ushort8;

static __device__ __forceinline__ unsigned short f2bf(float f) {
  return __builtin_bit_cast(unsigned short, (__bf16)f);
}

// ---------------- kernel 1: W [256][128] f32 -> Wt [128][256] bf16 (transposed) ----
__global__ void prep_wt_k(const float* __restrict__ W, unsigned short* __restrict__ Wt) {
  const int i = blockIdx.x * 256 + threadIdx.x;  // 32768 total
  const int k = i >> 7;   // 0..255
  const int n = i & 127;  // 0..127
  Wt[n * KD + k] = f2bf(W[i]);
}

// ---------------- kernel 2: h = x@W (bf16 MFMA), fused s_src/s_dst ----------------
// block = 256 thr = 4 waves; each wave does 16 rows x 128 cols, K=256 in 8 steps.
__global__ __launch_bounds__(256) void gemm_k(
    const float* __restrict__ x, const unsigned short* __restrict__ Wt,
    const float* __restrict__ a, unsigned short* __restrict__ h,
    float* __restrict__ ssrc, float* __restrict__ sdst) {
  const int lane = threadIdx.x & 63;
  const int wave = threadIdx.x >> 6;
  const int m0 = blockIdx.x * 64 + wave * 16;
  const int col = lane & 15;   // A-row / B-col / D-col low index
  const int kg = lane >> 4;    // k-group 0..3
  const int arow = m0 + col;
  const bool rowok = arow < NN;
  const float* __restrict__ xrow = x + (size_t)arow * KD;

  f32x4 acc[8];
#pragma unroll
  for (int i = 0; i < 8; ++i) acc[i] = (f32x4)0.0f;

#pragma unroll
  for (int k0 = 0; k0 < KD; k0 += 32) {
    const int kk = k0 + kg * 8;
    bf16x8 af = (bf16x8)(__bf16)0.0f;
    if (rowok) {
      const float4 f0 = *(const float4*)(xrow + kk);
      const float4 f1 = *(const float4*)(xrow + kk + 4);
      af[0] = (__bf16)f0.x; af[1] = (__bf16)f0.y; af[2] = (__bf16)f0.z; af[3] = (__bf16)f0.w;
      af[4] = (__bf16)f1.x; af[5] = (__bf16)f1.y; af[6] = (__bf16)f1.z; af[7] = (__bf16)f1.w;
    }
#pragma unroll
    for (int nt = 0; nt < 8; ++nt) {
      const ushort8 bu = *(const ushort8*)(Wt + (size_t)(nt * 16 + col) * KD + kk);
      const bf16x8 bf = __builtin_bit_cast(bf16x8, bu);
      acc[nt] = __builtin_amdgcn_mfma_f32_16x16x32_bf16(af, bf, acc[nt], 0, 0, 0);
    }
  }

  // C/D layout (m89-verified): col = lane&15, row = (lane>>4)*4 + r
  float ps[4] = {0.f, 0.f, 0.f, 0.f};
  float pd[4] = {0.f, 0.f, 0.f, 0.f};
#pragma unroll
  for (int nt = 0; nt < 8; ++nt) {
    const int n = nt * 16 + col;
    const float av = a[n];
    const float av2 = a[OD + n];
#pragma unroll
    for (int r = 0; r < 4; ++r) {
      const float v = acc[nt][r];
      const int row = m0 + kg * 4 + r;
      if (row < NN) h[(size_t)row * OD + n] = f2bf(v);
      ps[r] += v * av;
      pd[r] += v * av2;
    }
  }
  // reduce across the 16 lanes (cols) that share each row
#pragma unroll
  for (int off = 1; off < 16; off <<= 1) {
#pragma unroll
    for (int r = 0; r < 4; ++r) {
      ps[r] += __shfl_xor(ps[r], off, 64);
      pd[r] += __shfl_xor(pd[r], off, 64);
    }
  }
  if (col == 0) {
#pragma unroll
    for (int r = 0; r < 4; ++r) {
      const int row = m0 + kg * 4 + r;
      if (row < NN) { ssrc[row] = ps[r]; sdst[row] = pd[r]; }
    }
  }
}

// ---------------- kernel 3: per-src histogram -------------------------------------
__global__ void count_k(const int* __restrict__ src, int* __restrict__ cnt) {
  const int i = blockIdx.x * 256 + threadIdx.x;
  if (i < NE / 4) {
    const int4 s = *(const int4*)(src + i * 4);
    atomicAdd(&cnt[s.x], 1);
    atomicAdd(&cnt[s.y], 1);
    atomicAdd(&cnt[s.z], 1);
    atomicAdd(&cnt[s.w], 1);
  }
}

// ---------------- kernel 4a: block-local exclusive scan (1024/block) --------------
__global__ __launch_bounds__(1024) void scan1_k(const int* __restrict__ cnt,
                                                int* __restrict__ excl,
                                                int* __restrict__ bsum) {
  __shared__ int tmp[1024];
  const int t = threadIdx.x;
  const int i = blockIdx.x * 1024 + t;
  const int v = (i < NN) ? cnt[i] : 0;
  tmp[t] = v;
  __syncthreads();
#pragma unroll
  for (int off = 1; off < 1024; off <<= 1) {
    const int add = (t >= off) ? tmp[t - off] : 0;
    __syncthreads();
    tmp[t] += add;
    __syncthreads();
  }
  if (i < NN) excl[i] = tmp[t] - v;  // exclusive
  if (t == 1023) bsum[blockIdx.x] = tmp[1023];
}

// ---------------- kernel 4b: scan the 98 block sums -------------------------------
__global__ void scan2_k(int* __restrict__ bsum) {
  __shared__ int tmp[128];
  const int t = threadIdx.x;
  const int v = (t < 98) ? bsum[t] : 0;
  tmp[t] = v;
  __syncthreads();
#pragma unroll
  for (int off = 1; off < 128; off <<= 1) {
    const int add = (t >= off) ? tmp[t - off] : 0;
    __syncthreads();
    tmp[t] += add;
    __syncthreads();
  }
  if (t < 98) bsum[t] = tmp[t] - v;  // exclusive block offsets
}

// ---------------- kernel 5: recompute exp(e), place into CSR slot, denom ----------
__global__ void place_k(const int* __restrict__ el, const float* __restrict__ ssrc,
                        const float* __restrict__ sdst, const int* __restrict__ excl,
                        const int* __restrict__ bsum, int* __restrict__ cursor,
                        float* __restrict__ denom, int* __restrict__ sdsto,
                        float* __restrict__ sexo) {
  const int e = blockIdx.x * 256 + threadIdx.x;
  if (e >= NE) return;
  const int s = el[e];
  const int d = el[NE + e];
  const float sv = ssrc[s] + sdst[d];
  const float lr = sv > 0.f ? sv : 0.2f * sv;        // leaky_relu(0.2)
  const float ex = __expf(lr);                       // no max-shift needed: |lr| <~ 10
  const int pos = excl[s] + bsum[s >> 10] + atomicAdd(&cursor[s], 1);
  sdsto[pos] = d;
  sexo[pos] = ex;
  atomicAdd(&denom[s], ex);
}

// ---------------- kernel 6: wave-per-node gather-aggregate + ELU ------------------
__global__ __launch_bounds__(256) void aggr_k(
    const unsigned short* __restrict__ h, const int* __restrict__ sdsto,
    const float* __restrict__ sexo, const int* __restrict__ excl,
    const int* __restrict__ bsum, const int* __restrict__ cnt,
    const float* __restrict__ denom, float* __restrict__ out) {
  const int lane = threadIdx.x & 63;
  const int node = blockIdx.x * 4 + (threadIdx.x >> 6);  // grid covers exactly NN
  const int r0 = excl[node] + bsum[node >> 10];
  const int deg = cnt[node];
  const unsigned int* __restrict__ hp = (const unsigned int*)h;
  float a0 = 0.f, a1 = 0.f;
  for (int j = r0; j < r0 + deg; ++j) {
    const int d = sdsto[j];
    const float w = sexo[j];
    const unsigned int pk = hp[(size_t)d * 64 + lane];
    a0 += w * __builtin_bit_cast(float, pk << 16);
    a1 += w * __builtin_bit_cast(float, pk & 0xffff0000u);
  }
  const float inv = deg > 0 ? 1.0f / denom[node] : 0.f;
  float o0 = a0 * inv, o1 = a1 * inv;
  o0 = o0 > 0.f ? o0 : __expf(o0) - 1.f;  // elu alpha=1
  o1 = o1 > 0.f ? o1 : __expf(o1) - 1.f;
  *(float2*)(out + (size_t)node * OD + lane * 2) = make_float2(o0, o1);
}

extern "C" void kernel_launch(void* const* d_in, const int* in_sizes, int n_in,
                              void* d_out, int out_size, void* d_ws, size_t ws_size,
                              hipStream_t stream) {
  const float* x = (const float*)d_in[0];
  const int* el = (const int*)d_in[1];
  const float* W = (const float*)d_in[2];
  const float* a = (const float*)d_in[3];
  float* out = (float*)d_out;
  char* ws = (char*)d_ws;

  const size_t S = 400384;  // 100000*4 padded to 512
  int* cnt      = (int*)(ws + 0 * S);
  int* cursor   = (int*)(ws + 1 * S);
  float* denom  = (float*)(ws + 2 * S);
  int* excl     = (int*)(ws + 3 * S);
  float* ssrc   = (float*)(ws + 4 * S);
  float* sdst   = (float*)(ws + 5 * S);
  int* bsum     = (int*)(ws + 6 * S);               // 98 ints (4 KB reserved)
  unsigned short* Wt = (unsigned short*)(ws + 6 * S + 4096);          // 64 KB
  unsigned short* h  = (unsigned short*)(ws + 6 * S + 4096 + 65536);  // 25.6 MB
  char* after_h = ws + 6 * S + 4096 + 65536 + (size_t)NN * OD * 2;
  int* sdsto   = (int*)after_h;                      // 6.4 MB
  float* sexo  = (float*)(after_h + (size_t)NE * 4); // 6.4 MB
  // total ~= 41.3 MB

  // zero cnt / cursor / denom (contiguous) every launch (graph-replay safe)
  hipMemsetAsync(ws, 0, 3 * S, stream);

  prep_wt_k<<<128, 256, 0, stream>>>(W, Wt);
  gemm_k<<<(NN + 63) / 64, 256, 0, stream>>>(x, Wt, a, h, ssrc, sdst);
  count_k<<<(NE / 4 + 255) / 256, 256, 0, stream>>>(el, cnt);
  scan1_k<<<98, 1024, 0, stream>>>(cnt, excl, bsum);
  scan2_k<<<1, 128, 0, stream>>>(bsum);
  place_k<<<NE / 256, 256, 0, stream>>>(el, ssrc, sdst, excl, bsum, cursor, denom,
                                        sdsto, sexo);
  aggr_k<<<NN / 4, 256, 0, stream>>>(h, sdsto, sexo, excl, bsum, cnt, denom, out);
}

// Round 2
// 380.327 us; speedup vs baseline: 1.2049x; 1.2049x over previous
//
#include <hip/hip_runtime.h>
#include <hip/hip_bf16.h>
#include <cstdint>
#include <cstddef>

#define NN 100000
#define NE 1600000
#define KD 256
#define OD 128

typedef __attribute__((ext_vector_type(8))) __bf16 bf16x8;
typedef __attribute__((ext_vector_type(4))) float f32x4;
typedef __attribute__((ext_vector_type(8))) unsigned short ushort8;

static __device__ __forceinline__ unsigned short f2bf(float f) {
  return __builtin_bit_cast(unsigned short, (__bf16)f);
}

// ---------------- kernel 1: W [256][128] f32 -> Wt [128][256] bf16 (transposed) ----
__global__ void prep_wt_k(const float* __restrict__ W, unsigned short* __restrict__ Wt) {
  const int i = blockIdx.x * 256 + threadIdx.x;  // 32768 total
  const int k = i >> 7;   // 0..255
  const int n = i & 127;  // 0..127
  Wt[n * KD + k] = f2bf(W[i]);
}

// ---------------- kernel 2: h = x@W (bf16 MFMA), fused s_src/s_dst ----------------
__global__ __launch_bounds__(256) void gemm_k(
    const float* __restrict__ x, const unsigned short* __restrict__ Wt,
    const float* __restrict__ a, unsigned short* __restrict__ h,
    float* __restrict__ ssrc, float* __restrict__ sdst) {
  const int lane = threadIdx.x & 63;
  const int wave = threadIdx.x >> 6;
  const int m0 = blockIdx.x * 64 + wave * 16;
  const int col = lane & 15;   // A-row / B-col / D-col low index
  const int kg = lane >> 4;    // k-group 0..3
  const int arow = m0 + col;
  const bool rowok = arow < NN;
  const float* __restrict__ xrow = x + (size_t)arow * KD;

  f32x4 acc[8];
#pragma unroll
  for (int i = 0; i < 8; ++i) acc[i] = (f32x4)0.0f;

#pragma unroll
  for (int k0 = 0; k0 < KD; k0 += 32) {
    const int kk = k0 + kg * 8;
    bf16x8 af = (bf16x8)(__bf16)0.0f;
    if (rowok) {
      const float4 f0 = *(const float4*)(xrow + kk);
      const float4 f1 = *(const float4*)(xrow + kk + 4);
      af[0] = (__bf16)f0.x; af[1] = (__bf16)f0.y; af[2] = (__bf16)f0.z; af[3] = (__bf16)f0.w;
      af[4] = (__bf16)f1.x; af[5] = (__bf16)f1.y; af[6] = (__bf16)f1.z; af[7] = (__bf16)f1.w;
    }
#pragma unroll
    for (int nt = 0; nt < 8; ++nt) {
      const ushort8 bu = *(const ushort8*)(Wt + (size_t)(nt * 16 + col) * KD + kk);
      const bf16x8 bf = __builtin_bit_cast(bf16x8, bu);
      acc[nt] = __builtin_amdgcn_mfma_f32_16x16x32_bf16(af, bf, acc[nt], 0, 0, 0);
    }
  }

  // C/D layout: col = lane&15, row = (lane>>4)*4 + r
  float ps[4] = {0.f, 0.f, 0.f, 0.f};
  float pd[4] = {0.f, 0.f, 0.f, 0.f};
#pragma unroll
  for (int nt = 0; nt < 8; ++nt) {
    const int n = nt * 16 + col;
    const float av = a[n];
    const float av2 = a[OD + n];
#pragma unroll
    for (int r = 0; r < 4; ++r) {
      const float v = acc[nt][r];
      const int row = m0 + kg * 4 + r;
      if (row < NN) h[(size_t)row * OD + n] = f2bf(v);
      ps[r] += v * av;
      pd[r] += v * av2;
    }
  }
#pragma unroll
  for (int off = 1; off < 16; off <<= 1) {
#pragma unroll
    for (int r = 0; r < 4; ++r) {
      ps[r] += __shfl_xor(ps[r], off, 64);
      pd[r] += __shfl_xor(pd[r], off, 64);
    }
  }
  if (col == 0) {
#pragma unroll
    for (int r = 0; r < 4; ++r) {
      const int row = m0 + kg * 4 + r;
      if (row < NN) { ssrc[row] = ps[r]; sdst[row] = pd[r]; }
    }
  }
}

// ---------------- kernel 3: per-src histogram -------------------------------------
__global__ void count_k(const int* __restrict__ src, int* __restrict__ cnt) {
  const int i = blockIdx.x * 256 + threadIdx.x;
  if (i < NE / 4) {
    const int4 s = *(const int4*)(src + i * 4);
    atomicAdd(&cnt[s.x], 1);
    atomicAdd(&cnt[s.y], 1);
    atomicAdd(&cnt[s.z], 1);
    atomicAdd(&cnt[s.w], 1);
  }
}

// ---------------- kernel 4a: block-local exclusive scan (1024/block) --------------
__global__ __launch_bounds__(1024) void scan1_k(const int* __restrict__ cnt,
                                                int* __restrict__ excl,
                                                int* __restrict__ bsum) {
  __shared__ int tmp[1024];
  const int t = threadIdx.x;
  const int i = blockIdx.x * 1024 + t;
  const int v = (i < NN) ? cnt[i] : 0;
  tmp[t] = v;
  __syncthreads();
#pragma unroll
  for (int off = 1; off < 1024; off <<= 1) {
    const int add = (t >= off) ? tmp[t - off] : 0;
    __syncthreads();
    tmp[t] += add;
    __syncthreads();
  }
  if (i < NN) excl[i] = tmp[t] - v;  // exclusive
  if (t == 1023) bsum[blockIdx.x] = tmp[1023];
}

// ---------------- kernel 4b: scan the 98 block sums -------------------------------
__global__ void scan2_k(int* __restrict__ bsum) {
  __shared__ int tmp[128];
  const int t = threadIdx.x;
  const int v = (t < 98) ? bsum[t] : 0;
  tmp[t] = v;
  __syncthreads();
#pragma unroll
  for (int off = 1; off < 128; off <<= 1) {
    const int add = (t >= off) ? tmp[t - off] : 0;
    __syncthreads();
    tmp[t] += add;
    __syncthreads();
  }
  if (t < 98) bsum[t] = tmp[t] - v;  // exclusive block offsets
}

// ---------------- kernel 4c: rowstart = global prefix; cursor = rowstart ----------
__global__ void fixup_k(const int* __restrict__ excl, const int* __restrict__ bsum,
                        int* __restrict__ rowstart, int* __restrict__ cursor) {
  const int i = blockIdx.x * 256 + threadIdx.x;
  if (i < NN) {
    const int r = excl[i] + bsum[i >> 10];
    rowstart[i] = r;
    cursor[i] = r;
  }
}

// ---------------- kernel 5: exp(e) + packed scatter into CSR slot -----------------
__global__ void place_k(const int* __restrict__ el, const float* __restrict__ ssrc,
                        const float* __restrict__ sdst, int* __restrict__ cursor,
                        uint2* __restrict__ csr) {
  const int i = blockIdx.x * 256 + threadIdx.x;
  if (i >= NE / 4) return;
  const int4 s4 = *(const int4*)(el + (size_t)i * 4);
  const int4 d4 = *(const int4*)(el + NE + (size_t)i * 4);
  const int ss[4] = {s4.x, s4.y, s4.z, s4.w};
  const int dd[4] = {d4.x, d4.y, d4.z, d4.w};
#pragma unroll
  for (int u = 0; u < 4; ++u) {
    const int s = ss[u], d = dd[u];
    const float sv = ssrc[s] + sdst[d];
    const float lr = sv > 0.f ? sv : 0.2f * sv;   // leaky_relu(0.2)
    const float ex = __expf(lr);                  // bounded: |lr| <~ 10, no overflow
    const int pos = atomicAdd(&cursor[s], 1);
    csr[pos] = make_uint2((unsigned)d, __builtin_bit_cast(unsigned, ex));
  }
}

// ---------------- kernel 6: wave-per-node gather-aggregate + inline denom + ELU ---
__global__ __launch_bounds__(256) void aggr_k(
    const unsigned short* __restrict__ h, const uint2* __restrict__ csr,
    const int* __restrict__ rowstart, const int* __restrict__ cnt,
    float* __restrict__ out) {
  const int lane = threadIdx.x & 63;
  const int node = blockIdx.x * 4 + (threadIdx.x >> 6);  // grid covers exactly NN
  const int r0 = rowstart[node];
  const int deg = cnt[node];
  const unsigned int* __restrict__ hp = (const unsigned int*)h;
  float a0 = 0.f, a1 = 0.f, sw = 0.f;
  for (int j = r0; j < r0 + deg; ++j) {
    const uint2 en = csr[j];
    const int d = (int)en.x;
    const float w = __builtin_bit_cast(float, en.y);
    sw += w;
    const unsigned int pk = hp[(size_t)d * 64 + lane];
    a0 += w * __builtin_bit_cast(float, pk << 16);
    a1 += w * __builtin_bit_cast(float, pk & 0xffff0000u);
  }
  const float inv = deg > 0 ? 1.0f / sw : 0.f;
  float o0 = a0 * inv, o1 = a1 * inv;
  o0 = o0 > 0.f ? o0 : __expf(o0) - 1.f;  // elu alpha=1
  o1 = o1 > 0.f ? o1 : __expf(o1) - 1.f;
  *(float2*)(out + (size_t)node * OD + lane * 2) = make_float2(o0, o1);
}

extern "C" void kernel_launch(void* const* d_in, const int* in_sizes, int n_in,
                              void* d_out, int out_size, void* d_ws, size_t ws_size,
                              hipStream_t stream) {
  const float* x = (const float*)d_in[0];
  const int* el = (const int*)d_in[1];
  const float* W = (const float*)d_in[2];
  const float* a = (const float*)d_in[3];
  float* out = (float*)d_out;
  char* ws = (char*)d_ws;

  const size_t S = 400384;  // 100000*4 padded to 512
  int* cnt       = (int*)(ws + 0 * S);
  int* cursor    = (int*)(ws + 1 * S);
  int* excl      = (int*)(ws + 2 * S);
  int* rowstart  = (int*)(ws + 3 * S);
  float* ssrc    = (float*)(ws + 4 * S);
  float* sdst    = (float*)(ws + 5 * S);
  int* bsum      = (int*)(ws + 6 * S);               // 98 ints (4 KB reserved)
  unsigned short* Wt = (unsigned short*)(ws + 6 * S + 4096);          // 64 KB
  unsigned short* h  = (unsigned short*)(ws + 6 * S + 4096 + 65536);  // 25.6 MB
  uint2* csr = (uint2*)(ws + 6 * S + 4096 + 65536 + (size_t)NN * OD * 2);  // 12.8 MB

  // zero cnt only (graph-replay safe; everything else fully rewritten each launch)
  hipMemsetAsync(cnt, 0, S, stream);

  prep_wt_k<<<128, 256, 0, stream>>>(W, Wt);
  gemm_k<<<(NN + 63) / 64, 256, 0, stream>>>(x, Wt, a, h, ssrc, sdst);
  count_k<<<(NE / 4 + 255) / 256, 256, 0, stream>>>(el, cnt);
  scan1_k<<<98, 1024, 0, stream>>>(cnt, excl, bsum);
  scan2_k<<<1, 128, 0, stream>>>(bsum);
  fixup_k<<<(NN + 255) / 256, 256, 0, stream>>>(excl, bsum, rowstart, cursor);
  place_k<<<(NE / 4 + 255) / 256, 256, 0, stream>>>(el, ssrc, sdst, cursor, csr);
  aggr_k<<<NN / 4, 256, 0, stream>>>(h, csr, rowstart, cnt, out);
}

// Round 3
// 339.811 us; speedup vs baseline: 1.3485x; 1.1192x over previous
//
#include <hip/hip_runtime.h>
#include <hip/hip_bf16.h>
#include <cstdint>
#include <cstddef>

#define NN 100000
#define NE 1600000
#define KD 256
#define OD 128

typedef __attribute__((ext_vector_type(8))) __bf16 bf16x8;
typedef __attribute__((ext_vector_type(4))) float f32x4;
typedef __attribute__((ext_vector_type(8))) unsigned short ushort8;

static __device__ __forceinline__ unsigned short f2bf(float f) {
  return __builtin_bit_cast(unsigned short, (__bf16)f);
}
static __device__ __forceinline__ float bflo(unsigned p) {
  return __builtin_bit_cast(float, p << 16);
}
static __device__ __forceinline__ float bfhi(unsigned p) {
  return __builtin_bit_cast(float, p & 0xffff0000u);
}

// ---------------- kernel 1: W [256][128] f32 -> Wt [128][256] bf16 (transposed) ----
__global__ void prep_wt_k(const float* __restrict__ W, unsigned short* __restrict__ Wt) {
  const int i = blockIdx.x * 256 + threadIdx.x;  // 32768 total
  const int k = i >> 7;   // 0..255
  const int n = i & 127;  // 0..127
  Wt[n * KD + k] = f2bf(W[i]);
}

// ---------------- kernel 2: h = x@W (bf16 MFMA), fused s_src/s_dst ----------------
__global__ __launch_bounds__(256) void gemm_k(
    const float* __restrict__ x, const unsigned short* __restrict__ Wt,
    const float* __restrict__ a, unsigned short* __restrict__ h,
    float* __restrict__ ssrc, float* __restrict__ sdst) {
  const int lane = threadIdx.x & 63;
  const int wave = threadIdx.x >> 6;
  const int m0 = blockIdx.x * 64 + wave * 16;
  const int col = lane & 15;   // A-row / B-col / D-col low index
  const int kg = lane >> 4;    // k-group 0..3
  const int arow = m0 + col;
  const bool rowok = arow < NN;
  const float* __restrict__ xrow = x + (size_t)arow * KD;

  f32x4 acc[8];
#pragma unroll
  for (int i = 0; i < 8; ++i) acc[i] = (f32x4)0.0f;

#pragma unroll
  for (int k0 = 0; k0 < KD; k0 += 32) {
    const int kk = k0 + kg * 8;
    bf16x8 af = (bf16x8)(__bf16)0.0f;
    if (rowok) {
      const float4 f0 = *(const float4*)(xrow + kk);
      const float4 f1 = *(const float4*)(xrow + kk + 4);
      af[0] = (__bf16)f0.x; af[1] = (__bf16)f0.y; af[2] = (__bf16)f0.z; af[3] = (__bf16)f0.w;
      af[4] = (__bf16)f1.x; af[5] = (__bf16)f1.y; af[6] = (__bf16)f1.z; af[7] = (__bf16)f1.w;
    }
#pragma unroll
    for (int nt = 0; nt < 8; ++nt) {
      const ushort8 bu = *(const ushort8*)(Wt + (size_t)(nt * 16 + col) * KD + kk);
      const bf16x8 bf = __builtin_bit_cast(bf16x8, bu);
      acc[nt] = __builtin_amdgcn_mfma_f32_16x16x32_bf16(af, bf, acc[nt], 0, 0, 0);
    }
  }

  // C/D layout: col = lane&15, row = (lane>>4)*4 + r
  float ps[4] = {0.f, 0.f, 0.f, 0.f};
  float pd[4] = {0.f, 0.f, 0.f, 0.f};
#pragma unroll
  for (int nt = 0; nt < 8; ++nt) {
    const int n = nt * 16 + col;
    const float av = a[n];
    const float av2 = a[OD + n];
#pragma unroll
    for (int r = 0; r < 4; ++r) {
      const float v = acc[nt][r];
      const int row = m0 + kg * 4 + r;
      if (row < NN) h[(size_t)row * OD + n] = f2bf(v);
      ps[r] += v * av;
      pd[r] += v * av2;
    }
  }
#pragma unroll
  for (int off = 1; off < 16; off <<= 1) {
#pragma unroll
    for (int r = 0; r < 4; ++r) {
      ps[r] += __shfl_xor(ps[r], off, 64);
      pd[r] += __shfl_xor(pd[r], off, 64);
    }
  }
  if (col == 0) {
#pragma unroll
    for (int r = 0; r < 4; ++r) {
      const int row = m0 + kg * 4 + r;
      if (row < NN) { ssrc[row] = ps[r]; sdst[row] = pd[r]; }
    }
  }
}

// ---------------- kernel 3: per-src histogram -------------------------------------
__global__ void count_k(const int* __restrict__ src, int* __restrict__ cnt) {
  const int i = blockIdx.x * 256 + threadIdx.x;
  if (i < NE / 4) {
    const int4 s = *(const int4*)(src + i * 4);
    atomicAdd(&cnt[s.x], 1);
    atomicAdd(&cnt[s.y], 1);
    atomicAdd(&cnt[s.z], 1);
    atomicAdd(&cnt[s.w], 1);
  }
}

// ---------------- kernel 4a: block-local exclusive scan (1024/block) --------------
__global__ __launch_bounds__(1024) void scan1_k(const int* __restrict__ cnt,
                                                int* __restrict__ excl,
                                                int* __restrict__ bsum) {
  __shared__ int tmp[1024];
  const int t = threadIdx.x;
  const int i = blockIdx.x * 1024 + t;
  const int v = (i < NN) ? cnt[i] : 0;
  tmp[t] = v;
  __syncthreads();
#pragma unroll
  for (int off = 1; off < 1024; off <<= 1) {
    const int add = (t >= off) ? tmp[t - off] : 0;
    __syncthreads();
    tmp[t] += add;
    __syncthreads();
  }
  if (i < NN) excl[i] = tmp[t] - v;  // exclusive
  if (t == 1023) bsum[blockIdx.x] = tmp[1023];
}

// ---------------- kernel 4b: scan the 98 block sums -------------------------------
__global__ void scan2_k(int* __restrict__ bsum) {
  __shared__ int tmp[128];
  const int t = threadIdx.x;
  const int v = (t < 98) ? bsum[t] : 0;
  tmp[t] = v;
  __syncthreads();
#pragma unroll
  for (int off = 1; off < 128; off <<= 1) {
    const int add = (t >= off) ? tmp[t - off] : 0;
    __syncthreads();
    tmp[t] += add;
    __syncthreads();
  }
  if (t < 98) bsum[t] = tmp[t] - v;  // exclusive block offsets
}

// ---------------- kernel 4c: rowstart = global prefix; cursor = rowstart ----------
__global__ void fixup_k(const int* __restrict__ excl, const int* __restrict__ bsum,
                        int* __restrict__ rowstart, int* __restrict__ cursor) {
  const int i = blockIdx.x * 256 + threadIdx.x;
  if (i < NN) {
    const int r = excl[i] + bsum[i >> 10];
    rowstart[i] = r;
    cursor[i] = r;
  }
}

// ---------------- kernel 5: scatter dst into CSR slot (4 B entries) ---------------
__global__ void place_k(const int* __restrict__ el, int* __restrict__ cursor,
                        int* __restrict__ csrd) {
  const int i = blockIdx.x * 256 + threadIdx.x;
  if (i >= NE / 4) return;
  const int4 s4 = *(const int4*)(el + (size_t)i * 4);
  const int4 d4 = *(const int4*)(el + NE + (size_t)i * 4);
  const int ss[4] = {s4.x, s4.y, s4.z, s4.w};
  const int dd[4] = {d4.x, d4.y, d4.z, d4.w};
#pragma unroll
  for (int u = 0; u < 4; ++u) {
    const int pos = atomicAdd(&cursor[ss[u]], 1);
    csrd[pos] = dd[u];
  }
}

// ---------------- kernel 6: wave-per-node, 8 gathers in flight, fused softmax+ELU -
// lane-group g = lane>>4 handles edge slot g; lane sub = lane&15 covers cols sub*8..+7
__global__ __launch_bounds__(256) void aggr_k(
    const unsigned short* __restrict__ h, const int* __restrict__ csrd,
    const int* __restrict__ rowstart, const int* __restrict__ cnt,
    const float* __restrict__ ssrc, const float* __restrict__ sdst,
    float* __restrict__ out) {
  const int lane = threadIdx.x & 63;
  const int g = lane >> 4;
  const int sub = lane & 15;
  const int node = blockIdx.x * 4 + (threadIdx.x >> 6);  // grid covers exactly NN
  const int r0 = rowstart[node];
  const int deg = cnt[node];
  const int jend = r0 + deg;
  const float sbase = ssrc[node];
  const uint4* __restrict__ hp = (const uint4*)h;  // one h row = 16 uint4
  float acc[8] = {0.f, 0.f, 0.f, 0.f, 0.f, 0.f, 0.f, 0.f};
  float sw = 0.f;
  const int nit = (deg + 7) >> 3;  // 8 edges per iteration (4 groups x 2 slots)
  for (int it = 0; it < nit; ++it) {
    const int j0 = r0 + it * 8 + g;
    const int j1 = j0 + 4;
    const int d0 = csrd[j0 < jend ? j0 : r0];
    const int d1 = csrd[j1 < jend ? j1 : r0];
    const uint4 p0 = hp[(size_t)d0 * 16 + sub];
    const uint4 p1 = hp[(size_t)d1 * 16 + sub];
    float e0 = sbase + sdst[d0];
    float e1 = sbase + sdst[d1];
    e0 = e0 > 0.f ? e0 : 0.2f * e0;   // leaky_relu(0.2)
    e1 = e1 > 0.f ? e1 : 0.2f * e1;
    const float w0 = (j0 < jend) ? __expf(e0) : 0.f;  // bounded, no max-shift needed
    const float w1 = (j1 < jend) ? __expf(e1) : 0.f;
    sw += w0 + w1;
    const unsigned k0[4] = {p0.x, p0.y, p0.z, p0.w};
    const unsigned k1[4] = {p1.x, p1.y, p1.z, p1.w};
#pragma unroll
    for (int q = 0; q < 4; ++q) {
      acc[q * 2]     += w0 * bflo(k0[q]) + w1 * bflo(k1[q]);
      acc[q * 2 + 1] += w0 * bfhi(k0[q]) + w1 * bfhi(k1[q]);
    }
  }
  // reduce across the 4 edge-groups (same sub = same columns)
#pragma unroll
  for (int off = 16; off < 64; off <<= 1) {
    sw += __shfl_xor(sw, off, 64);
#pragma unroll
    for (int q = 0; q < 8; ++q) acc[q] += __shfl_xor(acc[q], off, 64);
  }
  const float inv = deg > 0 ? 1.0f / sw : 0.f;
  float o[8];
#pragma unroll
  for (int q = 0; q < 8; ++q) {
    const float v = acc[q] * inv;
    o[q] = v > 0.f ? v : __expf(v) - 1.f;  // elu alpha=1
  }
  if (lane < 16) {
    float4* op = (float4*)(out + (size_t)node * OD + sub * 8);
    op[0] = make_float4(o[0], o[1], o[2], o[3]);
    op[1] = make_float4(o[4], o[5], o[6], o[7]);
  }
}

extern "C" void kernel_launch(void* const* d_in, const int* in_sizes, int n_in,
                              void* d_out, int out_size, void* d_ws, size_t ws_size,
                              hipStream_t stream) {
  const float* x = (const float*)d_in[0];
  const int* el = (const int*)d_in[1];
  const float* W = (const float*)d_in[2];
  const float* a = (const float*)d_in[3];
  float* out = (float*)d_out;
  char* ws = (char*)d_ws;

  const size_t S = 400384;  // 100000*4 padded to 512
  int* cnt       = (int*)(ws + 0 * S);
  int* cursor    = (int*)(ws + 1 * S);
  int* excl      = (int*)(ws + 2 * S);
  int* rowstart  = (int*)(ws + 3 * S);
  float* ssrc    = (float*)(ws + 4 * S);
  float* sdst    = (float*)(ws + 5 * S);
  int* bsum      = (int*)(ws + 6 * S);               // 98 ints (4 KB reserved)
  unsigned short* Wt = (unsigned short*)(ws + 6 * S + 4096);          // 64 KB
  unsigned short* h  = (unsigned short*)(ws + 6 * S + 4096 + 65536);  // 25.6 MB
  int* csrd = (int*)(ws + 6 * S + 4096 + 65536 + (size_t)NN * OD * 2);  // 6.4 MB

  // zero cnt only (graph-replay safe; everything else fully rewritten each launch)
  hipMemsetAsync(cnt, 0, S, stream);

  prep_wt_k<<<128, 256, 0, stream>>>(W, Wt);
  gemm_k<<<(NN + 63) / 64, 256, 0, stream>>>(x, Wt, a, h, ssrc, sdst);
  count_k<<<(NE / 4 + 255) / 256, 256, 0, stream>>>(el, cnt);
  scan1_k<<<98, 1024, 0, stream>>>(cnt, excl, bsum);
  scan2_k<<<1, 128, 0, stream>>>(bsum);
  fixup_k<<<(NN + 255) / 256, 256, 0, stream>>>(excl, bsum, rowstart, cursor);
  place_k<<<(NE / 4 + 255) / 256, 256, 0, stream>>>(el, cursor, csrd);
  aggr_k<<<NN / 4, 256, 0, stream>>>(h, csrd, rowstart, cnt, ssrc, sdst, out);
}

// Round 4
// 185.449 us; speedup vs baseline: 2.4710x; 1.8324x over previous
//
#include <hip/hip_runtime.h>
#include <hip/hip_bf16.h>
#include <cstdint>
#include <cstddef>

#define NN 100000
#define NE 1600000
#define KD 256
#define OD 128
#define NB 391    // ceil(NN/256) buckets of 256 src nodes
#define CAP 8192  // staging capacity per bucket (mean 6250, sigma ~79)

typedef __attribute__((ext_vector_type(8))) __bf16 bf16x8;
typedef __attribute__((ext_vector_type(4))) float f32x4;
typedef __attribute__((ext_vector_type(8))) unsigned short ushort8;

static __device__ __forceinline__ unsigned short f2bf(float f) {
  return __builtin_bit_cast(unsigned short, (__bf16)f);
}
static __device__ __forceinline__ float bflo(unsigned p) {
  return __builtin_bit_cast(float, p << 16);
}
static __device__ __forceinline__ float bfhi(unsigned p) {
  return __builtin_bit_cast(float, p & 0xffff0000u);
}

// ---------------- kernel 1: W [256][128] f32 -> Wt [128][256] bf16 (transposed) ----
__global__ void prep_wt_k(const float* __restrict__ W, unsigned short* __restrict__ Wt) {
  const int i = blockIdx.x * 256 + threadIdx.x;  // 32768 total
  const int k = i >> 7;   // 0..255
  const int n = i & 127;  // 0..127
  Wt[n * KD + k] = f2bf(W[i]);
}

// ---------------- kernel 2: h = x@W (bf16 MFMA), fused s_src/s_dst ----------------
__global__ __launch_bounds__(256) void gemm_k(
    const float* __restrict__ x, const unsigned short* __restrict__ Wt,
    const float* __restrict__ a, unsigned short* __restrict__ h,
    float* __restrict__ ssrc, float* __restrict__ sdst) {
  const int lane = threadIdx.x & 63;
  const int wave = threadIdx.x >> 6;
  const int m0 = blockIdx.x * 64 + wave * 16;
  const int col = lane & 15;   // A-row / B-col / D-col low index
  const int kg = lane >> 4;    // k-group 0..3
  const int arow = m0 + col;
  const bool rowok = arow < NN;
  const float* __restrict__ xrow = x + (size_t)arow * KD;

  f32x4 acc[8];
#pragma unroll
  for (int i = 0; i < 8; ++i) acc[i] = (f32x4)0.0f;

#pragma unroll
  for (int k0 = 0; k0 < KD; k0 += 32) {
    const int kk = k0 + kg * 8;
    bf16x8 af = (bf16x8)(__bf16)0.0f;
    if (rowok) {
      const float4 f0 = *(const float4*)(xrow + kk);
      const float4 f1 = *(const float4*)(xrow + kk + 4);
      af[0] = (__bf16)f0.x; af[1] = (__bf16)f0.y; af[2] = (__bf16)f0.z; af[3] = (__bf16)f0.w;
      af[4] = (__bf16)f1.x; af[5] = (__bf16)f1.y; af[6] = (__bf16)f1.z; af[7] = (__bf16)f1.w;
    }
#pragma unroll
    for (int nt = 0; nt < 8; ++nt) {
      const ushort8 bu = *(const ushort8*)(Wt + (size_t)(nt * 16 + col) * KD + kk);
      const bf16x8 bf = __builtin_bit_cast(bf16x8, bu);
      acc[nt] = __builtin_amdgcn_mfma_f32_16x16x32_bf16(af, bf, acc[nt], 0, 0, 0);
    }
  }

  // C/D layout: col = lane&15, row = (lane>>4)*4 + r
  float ps[4] = {0.f, 0.f, 0.f, 0.f};
  float pd[4] = {0.f, 0.f, 0.f, 0.f};
#pragma unroll
  for (int nt = 0; nt < 8; ++nt) {
    const int n = nt * 16 + col;
    const float av = a[n];
    const float av2 = a[OD + n];
#pragma unroll
    for (int r = 0; r < 4; ++r) {
      const float v = acc[nt][r];
      const int row = m0 + kg * 4 + r;
      if (row < NN) h[(size_t)row * OD + n] = f2bf(v);
      ps[r] += v * av;
      pd[r] += v * av2;
    }
  }
#pragma unroll
  for (int off = 1; off < 16; off <<= 1) {
#pragma unroll
    for (int r = 0; r < 4; ++r) {
      ps[r] += __shfl_xor(ps[r], off, 64);
      pd[r] += __shfl_xor(pd[r], off, 64);
    }
  }
  if (col == 0) {
#pragma unroll
    for (int r = 0; r < 4; ++r) {
      const int row = m0 + kg * 4 + r;
      if (row < NN) { ssrc[row] = ps[r]; sdst[row] = pd[r]; }
    }
  }
}

// ---------------- kernel 3: init per-bucket staging cursors -----------------------
__global__ void init_bcur_k(int* __restrict__ bcur) {
  const int t = threadIdx.x;
  if (t < NB) bcur[t] = t * CAP;
}

// ---------------- kernel 4: pass 1 — LDS bucket-sort 2048 edges, write runs -------
__global__ __launch_bounds__(256) void bin_k(const int* __restrict__ el,
                                             int* __restrict__ bcur,
                                             unsigned* __restrict__ stage) {
  __shared__ int hist[NB + 1];
  __shared__ int off[NB + 1];
  __shared__ int cur[NB];
  __shared__ int delta[NB];
  __shared__ unsigned sorted[2048];
  __shared__ unsigned short bkid[2048];
  const int t = threadIdx.x;
  const int te = blockIdx.x * 2048 + t * 8;
  int s[8], d[8];
  bool valid[8];
#pragma unroll
  for (int u = 0; u < 8; ++u) valid[u] = (te + u) < NE;
  if (te + 7 < NE) {
    const int4 a0 = *(const int4*)(el + te);
    const int4 a1 = *(const int4*)(el + te + 4);
    const int4 b0 = *(const int4*)(el + NE + te);
    const int4 b1 = *(const int4*)(el + NE + te + 4);
    s[0] = a0.x; s[1] = a0.y; s[2] = a0.z; s[3] = a0.w;
    s[4] = a1.x; s[5] = a1.y; s[6] = a1.z; s[7] = a1.w;
    d[0] = b0.x; d[1] = b0.y; d[2] = b0.z; d[3] = b0.w;
    d[4] = b1.x; d[5] = b1.y; d[6] = b1.z; d[7] = b1.w;
  } else {
#pragma unroll
    for (int u = 0; u < 8; ++u) {
      s[u] = valid[u] ? el[te + u] : 0;
      d[u] = valid[u] ? el[NE + te + u] : 0;
    }
  }
  for (int i = t; i <= NB; i += 256) hist[i] = 0;
  __syncthreads();
#pragma unroll
  for (int u = 0; u < 8; ++u)
    if (valid[u]) atomicAdd(&hist[s[u] >> 8], 1);
  __syncthreads();
  // exclusive scan of hist[0..NB] by wave 0 (7 entries/lane)
  if (t < 64) {
    int v[7];
    int sum = 0;
#pragma unroll
    for (int i = 0; i < 7; ++i) {
      const int idx = t * 7 + i;
      v[i] = (idx <= NB) ? hist[idx] : 0;
      sum += v[i];
    }
    int pre = sum;
#pragma unroll
    for (int o = 1; o < 64; o <<= 1) {
      const int nb = __shfl_up(pre, o, 64);
      if (t >= o) pre += nb;
    }
    pre -= sum;  // exclusive across lanes
    int run = pre;
#pragma unroll
    for (int i = 0; i < 7; ++i) {
      const int idx = t * 7 + i;
      if (idx <= NB) off[idx] = run;
      run += v[i];
    }
  }
  __syncthreads();
  for (int i = t; i < NB; i += 256) cur[i] = off[i];
  __syncthreads();
#pragma unroll
  for (int u = 0; u < 8; ++u)
    if (valid[u]) {
      const int b = s[u] >> 8;
      const int p = atomicAdd(&cur[b], 1);
      sorted[p] = ((unsigned)(s[u] & 255) << 17) | (unsigned)d[u];
      bkid[p] = (unsigned short)b;
    }
  __syncthreads();
  for (int b = t; b < NB; b += 256) {
    const int len = off[b + 1] - off[b];
    if (len > 0) {
      const int gb = atomicAdd(&bcur[b], len);
      delta[b] = gb - off[b];
    }
  }
  __syncthreads();
  const int n = off[NB];
  for (int i = t; i < n; i += 256) {
    const int b = bkid[i];
    const int pos = delta[b] + i;
    if (pos < (b + 1) * CAP) stage[pos] = sorted[i];  // overflow clamp (never hit)
  }
}

// ---------------- kernel 5: scan 391 bucket totals -> bucket CSR bases ------------
__global__ __launch_bounds__(512) void bscan_k(const int* __restrict__ bcur,
                                               int* __restrict__ bbase) {
  __shared__ int tmp[512];
  const int t = threadIdx.x;
  int v = 0;
  if (t < NB) {
    v = bcur[t] - t * CAP;
    v = v > CAP ? CAP : v;
  }
  tmp[t] = v;
  __syncthreads();
  for (int o = 1; o < 512; o <<= 1) {
    const int add = (t >= o) ? tmp[t - o] : 0;
    __syncthreads();
    tmp[t] += add;
    __syncthreads();
  }
  if (t < NB) bbase[t] = tmp[t] - v;  // exclusive
}

// ---------------- kernel 6: pass 2 — per-bucket LDS hist/scan/place + cnt/rowstart -
__global__ __launch_bounds__(256) void place2_k(const unsigned* __restrict__ stage,
                                                const int* __restrict__ bcur,
                                                const int* __restrict__ bbase,
                                                int* __restrict__ csrd,
                                                int* __restrict__ cnt,
                                                int* __restrict__ rowstart) {
  __shared__ unsigned ebuf[CAP];   // 32 KB
  __shared__ int hist2[256];
  __shared__ int exc[256];
  __shared__ int cur2[256];
  const int b = blockIdx.x;
  const int t = threadIdx.x;
  int tot = bcur[b] - b * CAP;
  tot = tot > CAP ? CAP : tot;
  const int base = bbase[b];
  hist2[t] = 0;
  for (int i = t; i < tot; i += 256) ebuf[i] = stage[(size_t)b * CAP + i];
  __syncthreads();
  for (int i = t; i < tot; i += 256) atomicAdd(&hist2[ebuf[i] >> 17], 1);
  __syncthreads();
  // exclusive scan of hist2[0..255] by wave 0 (4/lane)
  if (t < 64) {
    int v[4];
    int sum = 0;
#pragma unroll
    for (int i = 0; i < 4; ++i) { v[i] = hist2[t * 4 + i]; sum += v[i]; }
    int pre = sum;
#pragma unroll
    for (int o = 1; o < 64; o <<= 1) {
      const int nb = __shfl_up(pre, o, 64);
      if (t >= o) pre += nb;
    }
    pre -= sum;
    int run = pre;
#pragma unroll
    for (int i = 0; i < 4; ++i) { exc[t * 4 + i] = run; run += v[i]; }
  }
  __syncthreads();
  const int node = b * 256 + t;
  if (node < NN) {
    cnt[node] = hist2[t];
    rowstart[node] = base + exc[t];
  }
  cur2[t] = exc[t];
  __syncthreads();
  for (int i = t; i < tot; i += 256) {
    const unsigned u = ebuf[i];
    const int p = atomicAdd(&cur2[u >> 17], 1);
    csrd[base + p] = (int)(u & 0x1ffffu);
  }
}

// ---------------- kernel 7: wave-per-node, 8 gathers in flight, fused softmax+ELU -
__global__ __launch_bounds__(256) void aggr_k(
    const unsigned short* __restrict__ h, const int* __restrict__ csrd,
    const int* __restrict__ rowstart, const int* __restrict__ cnt,
    const float* __restrict__ ssrc, const float* __restrict__ sdst,
    float* __restrict__ out) {
  const int lane = threadIdx.x & 63;
  const int g = lane >> 4;
  const int sub = lane & 15;
  const int node = blockIdx.x * 4 + (threadIdx.x >> 6);  // grid covers exactly NN
  const int r0 = rowstart[node];
  const int deg = cnt[node];
  const int jend = r0 + deg;
  const float sbase = ssrc[node];
  const uint4* __restrict__ hp = (const uint4*)h;  // one h row = 16 uint4
  float acc[8] = {0.f, 0.f, 0.f, 0.f, 0.f, 0.f, 0.f, 0.f};
  float sw = 0.f;
  const int nit = (deg + 7) >> 3;  // 8 edges per iteration (4 groups x 2 slots)
  for (int it = 0; it < nit; ++it) {
    const int j0 = r0 + it * 8 + g;
    const int j1 = j0 + 4;
    const int d0 = csrd[j0 < jend ? j0 : r0];
    const int d1 = csrd[j1 < jend ? j1 : r0];
    const uint4 p0 = hp[(size_t)d0 * 16 + sub];
    const uint4 p1 = hp[(size_t)d1 * 16 + sub];
    float e0 = sbase + sdst[d0];
    float e1 = sbase + sdst[d1];
    e0 = e0 > 0.f ? e0 : 0.2f * e0;   // leaky_relu(0.2)
    e1 = e1 > 0.f ? e1 : 0.2f * e1;
    const float w0 = (j0 < jend) ? __expf(e0) : 0.f;  // bounded, no max-shift needed
    const float w1 = (j1 < jend) ? __expf(e1) : 0.f;
    sw += w0 + w1;
    const unsigned k0[4] = {p0.x, p0.y, p0.z, p0.w};
    const unsigned k1[4] = {p1.x, p1.y, p1.z, p1.w};
#pragma unroll
    for (int q = 0; q < 4; ++q) {
      acc[q * 2]     += w0 * bflo(k0[q]) + w1 * bflo(k1[q]);
      acc[q * 2 + 1] += w0 * bfhi(k0[q]) + w1 * bfhi(k1[q]);
    }
  }
  // reduce across the 4 edge-groups (same sub = same columns)
#pragma unroll
  for (int off = 16; off < 64; off <<= 1) {
    sw += __shfl_xor(sw, off, 64);
#pragma unroll
    for (int q = 0; q < 8; ++q) acc[q] += __shfl_xor(acc[q], off, 64);
  }
  const float inv = deg > 0 ? 1.0f / sw : 0.f;
  float o[8];
#pragma unroll
  for (int q = 0; q < 8; ++q) {
    const float v = acc[q] * inv;
    o[q] = v > 0.f ? v : __expf(v) - 1.f;  // elu alpha=1
  }
  if (lane < 16) {
    float4* op = (float4*)(out + (size_t)node * OD + sub * 8);
    op[0] = make_float4(o[0], o[1], o[2], o[3]);
    op[1] = make_float4(o[4], o[5], o[6], o[7]);
  }
}

extern "C" void kernel_launch(void* const* d_in, const int* in_sizes, int n_in,
                              void* d_out, int out_size, void* d_ws, size_t ws_size,
                              hipStream_t stream) {
  const float* x = (const float*)d_in[0];
  const int* el = (const int*)d_in[1];
  const float* W = (const float*)d_in[2];
  const float* a = (const float*)d_in[3];
  float* out = (float*)d_out;
  char* ws = (char*)d_ws;

  const size_t S = 400384;  // 100000*4 padded to 512
  float* ssrc    = (float*)(ws + 0 * S);
  float* sdst    = (float*)(ws + 1 * S);
  int* cnt       = (int*)(ws + 2 * S);
  int* rowstart  = (int*)(ws + 3 * S);
  int* bcur      = (int*)(ws + 4 * S);          // 391 ints
  int* bbase     = (int*)(ws + 4 * S + 2048);   // 391 ints
  unsigned short* Wt = (unsigned short*)(ws + 4 * S + 8192);          // 64 KB
  unsigned short* h  = (unsigned short*)(ws + 4 * S + 8192 + 65536);  // 25.6 MB
  int* csrd = (int*)(ws + 4 * S + 8192 + 65536 + (size_t)NN * OD * 2);  // 6.4 MB
  // staging (12.81 MB) lives in d_out scratch space (51.2 MB); consumed by
  // place2_k before aggr_k rewrites every output element.
  unsigned* stage = (unsigned*)d_out;

  init_bcur_k<<<1, 512, 0, stream>>>(bcur);
  prep_wt_k<<<128, 256, 0, stream>>>(W, Wt);
  bin_k<<<(NE + 2047) / 2048, 256, 0, stream>>>(el, bcur, stage);
  gemm_k<<<(NN + 63) / 64, 256, 0, stream>>>(x, Wt, a, h, ssrc, sdst);
  bscan_k<<<1, 512, 0, stream>>>(bcur, bbase);
  place2_k<<<NB, 256, 0, stream>>>(stage, bcur, bbase, csrd, cnt, rowstart);
  aggr_k<<<NN / 4, 256, 0, stream>>>(h, csrd, rowstart, cnt, ssrc, sdst, out);
}

// Round 5
// 146.564 us; speedup vs baseline: 3.1266x; 1.2653x over previous
//
#include <hip/hip_runtime.h>
#include <hip/hip_bf16.h>
#include <cstdint>
#include <cstddef>

#define NN 100000
#define NE 1600000
#define KD 256
#define OD 128
#define NB 391    // ceil(NN/256) buckets of 256 src nodes
#define CAP 8192  // staging capacity per bucket (mean 6250, sigma ~79)

typedef __attribute__((ext_vector_type(8))) __bf16 bf16x8;
typedef __attribute__((ext_vector_type(4))) float f32x4;
typedef __attribute__((ext_vector_type(8))) unsigned short ushort8;

static __device__ __forceinline__ unsigned short f2bf(float f) {
  return __builtin_bit_cast(unsigned short, (__bf16)f);
}
static __device__ __forceinline__ float bflo(unsigned p) {
  return __builtin_bit_cast(float, p << 16);
}
static __device__ __forceinline__ float bfhi(unsigned p) {
  return __builtin_bit_cast(float, p & 0xffff0000u);
}

// ---------------- kernel 1: W [256][128] f32 -> Wt [128][256] bf16 (transposed) ----
__global__ void prep_wt_k(const float* __restrict__ W, unsigned short* __restrict__ Wt) {
  const int i = blockIdx.x * 256 + threadIdx.x;  // 32768 total
  const int k = i >> 7;   // 0..255
  const int n = i & 127;  // 0..127
  Wt[n * KD + k] = f2bf(W[i]);
}

// ---------------- kernel 2: h = x@W (bf16 MFMA, Wt in LDS), fused s_src/s_dst -----
// 512 thr = 8 waves; block does 128 rows (16/wave). Whole Wt (64 KB) staged in LDS,
// XOR-swizzled (byte ^= (row&7)<<4) so ds_read_b128 spreads over all bank groups.
__global__ __launch_bounds__(512, 4) void gemm_k(
    const float* __restrict__ x, const unsigned short* __restrict__ Wt,
    const float* __restrict__ a, unsigned short* __restrict__ h,
    float* __restrict__ ssrc, float* __restrict__ sdst) {
  __shared__ unsigned short Bl[32768];  // 64 KB: 128 rows x 512 B, swizzled
  const int t = threadIdx.x;
  // stage Wt[128][256] bf16 -> LDS (coalesced 16 B chunks, swizzled dest)
#pragma unroll
  for (int it = 0; it < 8; ++it) {
    const int c = it * 512 + t;        // 4096 chunks of 16 B
    const int r = c >> 5;
    const int c16 = c & 31;
    const ushort8 v = *(const ushort8*)(Wt + r * 256 + c16 * 8);
    const int byt = (r * 512 + c16 * 16) ^ ((r & 7) << 4);
    *(ushort8*)((char*)Bl + byt) = v;
  }
  const int lane = t & 63;
  const int wave = t >> 6;
  const int col = lane & 15;   // A-row / B-col / D-col low index
  const int kg = lane >> 4;    // k-group 0..3
  const int m0 = blockIdx.x * 128 + wave * 16;
  const int arow = m0 + col;
  const bool rowok = arow < NN;
  const float* __restrict__ xrow = x + (size_t)arow * KD;
  __syncthreads();

  f32x4 acc[8];
#pragma unroll
  for (int i = 0; i < 8; ++i) acc[i] = (f32x4)0.0f;

#pragma unroll
  for (int s = 0; s < 8; ++s) {
    const int kk = s * 32 + kg * 8;
    bf16x8 af = (bf16x8)(__bf16)0.0f;
    if (rowok) {
      const float4 f0 = *(const float4*)(xrow + kk);
      const float4 f1 = *(const float4*)(xrow + kk + 4);
      af[0] = (__bf16)f0.x; af[1] = (__bf16)f0.y; af[2] = (__bf16)f0.z; af[3] = (__bf16)f0.w;
      af[4] = (__bf16)f1.x; af[5] = (__bf16)f1.y; af[6] = (__bf16)f1.z; af[7] = (__bf16)f1.w;
    }
#pragma unroll
    for (int nt = 0; nt < 8; ++nt) {
      const int n = nt * 16 + col;
      const int byt = (n * 512 + s * 64 + kg * 16) ^ ((col & 7) << 4);
      const ushort8 bu = *(const ushort8*)((const char*)Bl + byt);
      const bf16x8 bf = __builtin_bit_cast(bf16x8, bu);
      acc[nt] = __builtin_amdgcn_mfma_f32_16x16x32_bf16(af, bf, acc[nt], 0, 0, 0);
    }
  }

  // C/D layout: col = lane&15, row = (lane>>4)*4 + r
  float ps[4] = {0.f, 0.f, 0.f, 0.f};
  float pd[4] = {0.f, 0.f, 0.f, 0.f};
#pragma unroll
  for (int nt = 0; nt < 8; ++nt) {
    const int n = nt * 16 + col;
    const float av = a[n];
    const float av2 = a[OD + n];
#pragma unroll
    for (int r = 0; r < 4; ++r) {
      const float v = acc[nt][r];
      const int row = m0 + kg * 4 + r;
      if (row < NN) h[(size_t)row * OD + n] = f2bf(v);
      ps[r] += v * av;
      pd[r] += v * av2;
    }
  }
#pragma unroll
  for (int off = 1; off < 16; off <<= 1) {
#pragma unroll
    for (int r = 0; r < 4; ++r) {
      ps[r] += __shfl_xor(ps[r], off, 64);
      pd[r] += __shfl_xor(pd[r], off, 64);
    }
  }
  if (col == 0) {
#pragma unroll
    for (int r = 0; r < 4; ++r) {
      const int row = m0 + kg * 4 + r;
      if (row < NN) { ssrc[row] = ps[r]; sdst[row] = pd[r]; }
    }
  }
}

// ---------------- kernel 3: init per-bucket staging cursors -----------------------
__global__ void init_bcur_k(int* __restrict__ bcur) {
  const int t = threadIdx.x;
  if (t < NB) bcur[t] = t * CAP;
}

// ---------------- kernel 4: pass 1 — LDS bucket-sort 2048 edges, write runs -------
__global__ __launch_bounds__(256) void bin_k(const int* __restrict__ el,
                                             int* __restrict__ bcur,
                                             unsigned* __restrict__ stage) {
  __shared__ int hist[NB + 1];
  __shared__ int off[NB + 1];
  __shared__ int cur[NB];
  __shared__ int delta[NB];
  __shared__ unsigned sorted[2048];
  __shared__ unsigned short bkid[2048];
  const int t = threadIdx.x;
  const int te = blockIdx.x * 2048 + t * 8;
  int s[8], d[8];
  bool valid[8];
#pragma unroll
  for (int u = 0; u < 8; ++u) valid[u] = (te + u) < NE;
  if (te + 7 < NE) {
    const int4 a0 = *(const int4*)(el + te);
    const int4 a1 = *(const int4*)(el + te + 4);
    const int4 b0 = *(const int4*)(el + NE + te);
    const int4 b1 = *(const int4*)(el + NE + te + 4);
    s[0] = a0.x; s[1] = a0.y; s[2] = a0.z; s[3] = a0.w;
    s[4] = a1.x; s[5] = a1.y; s[6] = a1.z; s[7] = a1.w;
    d[0] = b0.x; d[1] = b0.y; d[2] = b0.z; d[3] = b0.w;
    d[4] = b1.x; d[5] = b1.y; d[6] = b1.z; d[7] = b1.w;
  } else {
#pragma unroll
    for (int u = 0; u < 8; ++u) {
      s[u] = valid[u] ? el[te + u] : 0;
      d[u] = valid[u] ? el[NE + te + u] : 0;
    }
  }
  for (int i = t; i <= NB; i += 256) hist[i] = 0;
  __syncthreads();
#pragma unroll
  for (int u = 0; u < 8; ++u)
    if (valid[u]) atomicAdd(&hist[s[u] >> 8], 1);
  __syncthreads();
  // exclusive scan of hist[0..NB] by wave 0 (7 entries/lane)
  if (t < 64) {
    int v[7];
    int sum = 0;
#pragma unroll
    for (int i = 0; i < 7; ++i) {
      const int idx = t * 7 + i;
      v[i] = (idx <= NB) ? hist[idx] : 0;
      sum += v[i];
    }
    int pre = sum;
#pragma unroll
    for (int o = 1; o < 64; o <<= 1) {
      const int nb = __shfl_up(pre, o, 64);
      if (t >= o) pre += nb;
    }
    pre -= sum;  // exclusive across lanes
    int run = pre;
#pragma unroll
    for (int i = 0; i < 7; ++i) {
      const int idx = t * 7 + i;
      if (idx <= NB) off[idx] = run;
      run += v[i];
    }
  }
  __syncthreads();
  for (int i = t; i < NB; i += 256) cur[i] = off[i];
  __syncthreads();
#pragma unroll
  for (int u = 0; u < 8; ++u)
    if (valid[u]) {
      const int b = s[u] >> 8;
      const int p = atomicAdd(&cur[b], 1);
      sorted[p] = ((unsigned)(s[u] & 255) << 17) | (unsigned)d[u];
      bkid[p] = (unsigned short)b;
    }
  __syncthreads();
  for (int b = t; b < NB; b += 256) {
    const int len = off[b + 1] - off[b];
    if (len > 0) {
      const int gb = atomicAdd(&bcur[b], len);
      delta[b] = gb - off[b];
    }
  }
  __syncthreads();
  const int n = off[NB];
  for (int i = t; i < n; i += 256) {
    const int b = bkid[i];
    const int pos = delta[b] + i;
    if (pos < (b + 1) * CAP) stage[pos] = sorted[i];  // overflow clamp (never hit)
  }
}

// ---------------- kernel 5: scan 391 bucket totals -> bucket CSR bases ------------
__global__ __launch_bounds__(512) void bscan_k(const int* __restrict__ bcur,
                                               int* __restrict__ bbase) {
  __shared__ int tmp[512];
  const int t = threadIdx.x;
  int v = 0;
  if (t < NB) {
    v = bcur[t] - t * CAP;
    v = v > CAP ? CAP : v;
  }
  tmp[t] = v;
  __syncthreads();
  for (int o = 1; o < 512; o <<= 1) {
    const int add = (t >= o) ? tmp[t - o] : 0;
    __syncthreads();
    tmp[t] += add;
    __syncthreads();
  }
  if (t < NB) bbase[t] = tmp[t] - v;  // exclusive
}

// ---------------- kernel 6: pass 2 — per-bucket LDS hist/scan/place + cnt/rowstart -
__global__ __launch_bounds__(256) void place2_k(const unsigned* __restrict__ stage,
                                                const int* __restrict__ bcur,
                                                const int* __restrict__ bbase,
                                                int* __restrict__ csrd,
                                                int* __restrict__ cnt,
                                                int* __restrict__ rowstart) {
  __shared__ unsigned ebuf[CAP];   // 32 KB
  __shared__ int hist2[256];
  __shared__ int exc[256];
  __shared__ int cur2[256];
  const int b = blockIdx.x;
  const int t = threadIdx.x;
  int tot = bcur[b] - b * CAP;
  tot = tot > CAP ? CAP : tot;
  const int base = bbase[b];
  hist2[t] = 0;
  for (int i = t; i < tot; i += 256) ebuf[i] = stage[(size_t)b * CAP + i];
  __syncthreads();
  for (int i = t; i < tot; i += 256) atomicAdd(&hist2[ebuf[i] >> 17], 1);
  __syncthreads();
  // exclusive scan of hist2[0..255] by wave 0 (4/lane)
  if (t < 64) {
    int v[4];
    int sum = 0;
#pragma unroll
    for (int i = 0; i < 4; ++i) { v[i] = hist2[t * 4 + i]; sum += v[i]; }
    int pre = sum;
#pragma unroll
    for (int o = 1; o < 64; o <<= 1) {
      const int nb = __shfl_up(pre, o, 64);
      if (t >= o) pre += nb;
    }
    pre -= sum;
    int run = pre;
#pragma unroll
    for (int i = 0; i < 4; ++i) { exc[t * 4 + i] = run; run += v[i]; }
  }
  __syncthreads();
  const int node = b * 256 + t;
  if (node < NN) {
    cnt[node] = hist2[t];
    rowstart[node] = base + exc[t];
  }
  cur2[t] = exc[t];
  __syncthreads();
  for (int i = t; i < tot; i += 256) {
    const unsigned u = ebuf[i];
    const int p = atomicAdd(&cur2[u >> 17], 1);
    csrd[base + p] = (int)(u & 0x1ffffu);
  }
}

// ---------------- kernel 7: wave-per-node, 8 gathers in flight, fused softmax+ELU -
__global__ __launch_bounds__(256) void aggr_k(
    const unsigned short* __restrict__ h, const int* __restrict__ csrd,
    const int* __restrict__ rowstart, const int* __restrict__ cnt,
    const float* __restrict__ ssrc, const float* __restrict__ sdst,
    float* __restrict__ out) {
  const int lane = threadIdx.x & 63;
  const int g = lane >> 4;
  const int sub = lane & 15;
  const int node = blockIdx.x * 4 + (threadIdx.x >> 6);  // grid covers exactly NN
  const int r0 = rowstart[node];
  const int deg = cnt[node];
  const int jend = r0 + deg;
  const float sbase = ssrc[node];
  const uint4* __restrict__ hp = (const uint4*)h;  // one h row = 16 uint4
  float acc[8] = {0.f, 0.f, 0.f, 0.f, 0.f, 0.f, 0.f, 0.f};
  float sw = 0.f;
  const int nit = (deg + 7) >> 3;  // 8 edges per iteration (4 groups x 2 slots)
  for (int it = 0; it < nit; ++it) {
    const int j0 = r0 + it * 8 + g;
    const int j1 = j0 + 4;
    const int d0 = csrd[j0 < jend ? j0 : r0];
    const int d1 = csrd[j1 < jend ? j1 : r0];
    const uint4 p0 = hp[(size_t)d0 * 16 + sub];
    const uint4 p1 = hp[(size_t)d1 * 16 + sub];
    float e0 = sbase + sdst[d0];
    float e1 = sbase + sdst[d1];
    e0 = e0 > 0.f ? e0 : 0.2f * e0;   // leaky_relu(0.2)
    e1 = e1 > 0.f ? e1 : 0.2f * e1;
    const float w0 = (j0 < jend) ? __expf(e0) : 0.f;  // bounded, no max-shift needed
    const float w1 = (j1 < jend) ? __expf(e1) : 0.f;
    sw += w0 + w1;
    const unsigned k0[4] = {p0.x, p0.y, p0.z, p0.w};
    const unsigned k1[4] = {p1.x, p1.y, p1.z, p1.w};
#pragma unroll
    for (int q = 0; q < 4; ++q) {
      acc[q * 2]     += w0 * bflo(k0[q]) + w1 * bflo(k1[q]);
      acc[q * 2 + 1] += w0 * bfhi(k0[q]) + w1 * bfhi(k1[q]);
    }
  }
  // reduce across the 4 edge-groups (same sub = same columns)
#pragma unroll
  for (int off = 16; off < 64; off <<= 1) {
    sw += __shfl_xor(sw, off, 64);
#pragma unroll
    for (int q = 0; q < 8; ++q) acc[q] += __shfl_xor(acc[q], off, 64);
  }
  const float inv = deg > 0 ? 1.0f / sw : 0.f;
  float o[8];
#pragma unroll
  for (int q = 0; q < 8; ++q) {
    const float v = acc[q] * inv;
    o[q] = v > 0.f ? v : __expf(v) - 1.f;  // elu alpha=1
  }
  if (lane < 16) {
    float4* op = (float4*)(out + (size_t)node * OD + sub * 8);
    op[0] = make_float4(o[0], o[1], o[2], o[3]);
    op[1] = make_float4(o[4], o[5], o[6], o[7]);
  }
}

extern "C" void kernel_launch(void* const* d_in, const int* in_sizes, int n_in,
                              void* d_out, int out_size, void* d_ws, size_t ws_size,
                              hipStream_t stream) {
  const float* x = (const float*)d_in[0];
  const int* el = (const int*)d_in[1];
  const float* W = (const float*)d_in[2];
  const float* a = (const float*)d_in[3];
  float* out = (float*)d_out;
  char* ws = (char*)d_ws;

  const size_t S = 400384;  // 100000*4 padded to 512
  float* ssrc    = (float*)(ws + 0 * S);
  float* sdst    = (float*)(ws + 1 * S);
  int* cnt       = (int*)(ws + 2 * S);
  int* rowstart  = (int*)(ws + 3 * S);
  int* bcur      = (int*)(ws + 4 * S);          // 391 ints
  int* bbase     = (int*)(ws + 4 * S + 2048);   // 391 ints
  unsigned short* Wt = (unsigned short*)(ws + 4 * S + 8192);          // 64 KB
  unsigned short* h  = (unsigned short*)(ws + 4 * S + 8192 + 65536);  // 25.6 MB
  int* csrd = (int*)(ws + 4 * S + 8192 + 65536 + (size_t)NN * OD * 2);  // 6.4 MB
  // staging (12.81 MB) lives in d_out scratch space (51.2 MB); consumed by
  // place2_k before aggr_k rewrites every output element.
  unsigned* stage = (unsigned*)d_out;

  init_bcur_k<<<1, 512, 0, stream>>>(bcur);
  prep_wt_k<<<128, 256, 0, stream>>>(W, Wt);
  bin_k<<<(NE + 2047) / 2048, 256, 0, stream>>>(el, bcur, stage);
  gemm_k<<<(NN + 127) / 128, 512, 0, stream>>>(x, Wt, a, h, ssrc, sdst);
  bscan_k<<<1, 512, 0, stream>>>(bcur, bbase);
  place2_k<<<NB, 256, 0, stream>>>(stage, bcur, bbase, csrd, cnt, rowstart);
  aggr_k<<<NN / 4, 256, 0, stream>>>(h, csrd, rowstart, cnt, ssrc, sdst, out);
}

// Round 6
// 137.388 us; speedup vs baseline: 3.3354x; 1.0668x over previous
//
#include <hip/hip_runtime.h>
#include <hip/hip_bf16.h>
#include <cstdint>
#include <cstddef>

#define NN 100000
#define NE 1600000
#define KD 256
#define OD 128
#define NB 391     // ceil(NN/256) buckets of 256 src nodes
#define CAP 8192   // staging capacity per bucket (mean 6250, sigma ~79)
#define NGB 782    // gemm blocks in fused kernel (128 rows each)

typedef __attribute__((ext_vector_type(8))) __bf16 bf16x8;
typedef __attribute__((ext_vector_type(4))) float f32x4;
typedef __attribute__((ext_vector_type(8))) unsigned short ushort8;

static __device__ __forceinline__ unsigned short f2bf(float f) {
  return __builtin_bit_cast(unsigned short, (__bf16)f);
}
static __device__ __forceinline__ float bflo(unsigned p) {
  return __builtin_bit_cast(float, p << 16);
}
static __device__ __forceinline__ float bfhi(unsigned p) {
  return __builtin_bit_cast(float, p & 0xffff0000u);
}

// ---------------- kernel 1: W -> Wt bf16 transposed; also init bcur ---------------
__global__ void prep_wt_k(const float* __restrict__ W, unsigned short* __restrict__ Wt,
                          int* __restrict__ bcur) {
  const int i = blockIdx.x * 256 + threadIdx.x;  // 32768 total
  const int k = i >> 7;   // 0..255
  const int n = i & 127;  // 0..127
  Wt[n * KD + k] = f2bf(W[i]);
  if (i < NB) bcur[i] = i * CAP;
}

// ---------------- kernel 2: FUSED  gemm (blocks 0..781) | bin (782..1172) ---------
// gemm: 8 waves, 128 rows/block, whole Wt in LDS (XOR-swizzled), MFMA 16x16x32.
// bin : 512 thr, 4096 edges/block, LDS bucket-sort by src>>8, append runs to stage.
__global__ __launch_bounds__(512, 4) void fused_k(
    const float* __restrict__ x, const unsigned short* __restrict__ Wt,
    const float* __restrict__ a, unsigned short* __restrict__ h,
    float* __restrict__ ssrc, float* __restrict__ sdst,
    const int* __restrict__ el, int* __restrict__ bcur,
    unsigned* __restrict__ stage) {
  __shared__ alignas(16) char smem[65536];
  const int t = threadIdx.x;

  if (blockIdx.x < NGB) {
    // ------------------------- GEMM part -------------------------
    unsigned short* Bl = (unsigned short*)smem;  // 128 rows x 512 B, swizzled
#pragma unroll
    for (int it = 0; it < 8; ++it) {
      const int c = it * 512 + t;        // 4096 chunks of 16 B
      const int r = c >> 5;
      const int c16 = c & 31;
      const ushort8 v = *(const ushort8*)(Wt + r * 256 + c16 * 8);
      const int byt = (r * 512 + c16 * 16) ^ ((r & 7) << 4);
      *(ushort8*)((char*)Bl + byt) = v;
    }
    const int lane = t & 63;
    const int wave = t >> 6;
    const int col = lane & 15;
    const int kg = lane >> 4;
    const int m0 = blockIdx.x * 128 + wave * 16;
    const int arow = m0 + col;
    const bool rowok = arow < NN;
    const float* __restrict__ xrow = x + (size_t)arow * KD;
    __syncthreads();

    f32x4 acc[8];
#pragma unroll
    for (int i = 0; i < 8; ++i) acc[i] = (f32x4)0.0f;

#pragma unroll
    for (int s = 0; s < 8; ++s) {
      const int kk = s * 32 + kg * 8;
      bf16x8 af = (bf16x8)(__bf16)0.0f;
      if (rowok) {
        const float4 f0 = *(const float4*)(xrow + kk);
        const float4 f1 = *(const float4*)(xrow + kk + 4);
        af[0] = (__bf16)f0.x; af[1] = (__bf16)f0.y; af[2] = (__bf16)f0.z; af[3] = (__bf16)f0.w;
        af[4] = (__bf16)f1.x; af[5] = (__bf16)f1.y; af[6] = (__bf16)f1.z; af[7] = (__bf16)f1.w;
      }
#pragma unroll
      for (int nt = 0; nt < 8; ++nt) {
        const int n = nt * 16 + col;
        const int byt = (n * 512 + s * 64 + kg * 16) ^ ((col & 7) << 4);
        const ushort8 bu = *(const ushort8*)((const char*)Bl + byt);
        const bf16x8 bf = __builtin_bit_cast(bf16x8, bu);
        acc[nt] = __builtin_amdgcn_mfma_f32_16x16x32_bf16(af, bf, acc[nt], 0, 0, 0);
      }
    }

    // C/D layout: col = lane&15, row = (lane>>4)*4 + r
    float ps[4] = {0.f, 0.f, 0.f, 0.f};
    float pd[4] = {0.f, 0.f, 0.f, 0.f};
#pragma unroll
    for (int nt = 0; nt < 8; ++nt) {
      const int n = nt * 16 + col;
      const float av = a[n];
      const float av2 = a[OD + n];
#pragma unroll
      for (int r = 0; r < 4; ++r) {
        const float v = acc[nt][r];
        const int row = m0 + kg * 4 + r;
        if (row < NN) h[(size_t)row * OD + n] = f2bf(v);
        ps[r] += v * av;
        pd[r] += v * av2;
      }
    }
#pragma unroll
    for (int off = 1; off < 16; off <<= 1) {
#pragma unroll
      for (int r = 0; r < 4; ++r) {
        ps[r] += __shfl_xor(ps[r], off, 64);
        pd[r] += __shfl_xor(pd[r], off, 64);
      }
    }
    if (col == 0) {
#pragma unroll
      for (int r = 0; r < 4; ++r) {
        const int row = m0 + kg * 4 + r;
        // pre-scale scores by log2(e): aggr uses exp2 (leaky commutes with +scale)
        if (row < NN) {
          ssrc[row] = ps[r] * 1.442695041f;
          sdst[row] = pd[r] * 1.442695041f;
        }
      }
    }
  } else {
    // ------------------------- BIN part -------------------------
    unsigned* sorted = (unsigned*)smem;                       // 16384 B
    unsigned short* bkid = (unsigned short*)(smem + 16384);   // 8192 B
    int* hist  = (int*)(smem + 24576);                        // 392*4
    int* off   = (int*)(smem + 26144);                        // 392*4
    int* cur   = (int*)(smem + 27712);                        // 391*4
    int* delta = (int*)(smem + 29276);                        // 391*4
    const int te = (blockIdx.x - NGB) * 4096 + t * 8;
    int s[8], d[8];
    bool valid[8];
#pragma unroll
    for (int u = 0; u < 8; ++u) valid[u] = (te + u) < NE;
    if (te + 7 < NE) {
      const int4 a0 = *(const int4*)(el + te);
      const int4 a1 = *(const int4*)(el + te + 4);
      const int4 b0 = *(const int4*)(el + NE + te);
      const int4 b1 = *(const int4*)(el + NE + te + 4);
      s[0] = a0.x; s[1] = a0.y; s[2] = a0.z; s[3] = a0.w;
      s[4] = a1.x; s[5] = a1.y; s[6] = a1.z; s[7] = a1.w;
      d[0] = b0.x; d[1] = b0.y; d[2] = b0.z; d[3] = b0.w;
      d[4] = b1.x; d[5] = b1.y; d[6] = b1.z; d[7] = b1.w;
    } else {
#pragma unroll
      for (int u = 0; u < 8; ++u) {
        s[u] = valid[u] ? el[te + u] : 0;
        d[u] = valid[u] ? el[NE + te + u] : 0;
      }
    }
    for (int i = t; i <= NB; i += 512) hist[i] = 0;
    __syncthreads();
#pragma unroll
    for (int u = 0; u < 8; ++u)
      if (valid[u]) atomicAdd(&hist[s[u] >> 8], 1);
    __syncthreads();
    // exclusive scan of hist[0..NB] by wave 0 (7 entries/lane)
    if (t < 64) {
      int v[7];
      int sum = 0;
#pragma unroll
      for (int i = 0; i < 7; ++i) {
        const int idx = t * 7 + i;
        v[i] = (idx <= NB) ? hist[idx] : 0;
        sum += v[i];
      }
      int pre = sum;
#pragma unroll
      for (int o = 1; o < 64; o <<= 1) {
        const int nb = __shfl_up(pre, o, 64);
        if (t >= o) pre += nb;
      }
      pre -= sum;  // exclusive across lanes
      int run = pre;
#pragma unroll
      for (int i = 0; i < 7; ++i) {
        const int idx = t * 7 + i;
        if (idx <= NB) off[idx] = run;
        run += v[i];
      }
    }
    __syncthreads();
    for (int i = t; i < NB; i += 512) cur[i] = off[i];
    __syncthreads();
#pragma unroll
    for (int u = 0; u < 8; ++u)
      if (valid[u]) {
        const int b = s[u] >> 8;
        const int p = atomicAdd(&cur[b], 1);
        sorted[p] = ((unsigned)(s[u] & 255) << 17) | (unsigned)d[u];
        bkid[p] = (unsigned short)b;
      }
    __syncthreads();
    for (int b = t; b < NB; b += 512) {
      const int len = off[b + 1] - off[b];
      if (len > 0) {
        const int gb = atomicAdd(&bcur[b], len);
        delta[b] = gb - off[b];
      }
    }
    __syncthreads();
    const int n = off[NB];
    for (int i = t; i < n; i += 512) {
      const int b = bkid[i];
      const int pos = delta[b] + i;
      if (pos < (b + 1) * CAP) stage[pos] = sorted[i];  // overflow clamp (never hit)
    }
  }
}

// ---------------- kernel 3: scan 391 bucket totals -> bucket CSR bases ------------
__global__ __launch_bounds__(512) void bscan_k(const int* __restrict__ bcur,
                                               int* __restrict__ bbase) {
  __shared__ int tmp[512];
  const int t = threadIdx.x;
  int v = 0;
  if (t < NB) {
    v = bcur[t] - t * CAP;
    v = v > CAP ? CAP : v;
  }
  tmp[t] = v;
  __syncthreads();
  for (int o = 1; o < 512; o <<= 1) {
    const int add = (t >= o) ? tmp[t - o] : 0;
    __syncthreads();
    tmp[t] += add;
    __syncthreads();
  }
  if (t < NB) bbase[t] = tmp[t] - v;  // exclusive
}

// ---------------- kernel 4: per-bucket LDS hist/scan/place + cnt/rowstart ---------
__global__ __launch_bounds__(256) void place2_k(const unsigned* __restrict__ stage,
                                                const int* __restrict__ bcur,
                                                const int* __restrict__ bbase,
                                                int* __restrict__ csrd,
                                                int* __restrict__ cnt,
                                                int* __restrict__ rowstart) {
  __shared__ unsigned ebuf[CAP];   // 32 KB
  __shared__ int hist2[256];
  __shared__ int exc[256];
  __shared__ int cur2[256];
  const int b = blockIdx.x;
  const int t = threadIdx.x;
  int tot = bcur[b] - b * CAP;
  tot = tot > CAP ? CAP : tot;
  const int base = bbase[b];
  hist2[t] = 0;
  for (int i = t; i < tot; i += 256) ebuf[i] = stage[(size_t)b * CAP + i];
  __syncthreads();
  for (int i = t; i < tot; i += 256) atomicAdd(&hist2[ebuf[i] >> 17], 1);
  __syncthreads();
  // exclusive scan of hist2[0..255] by wave 0 (4/lane)
  if (t < 64) {
    int v[4];
    int sum = 0;
#pragma unroll
    for (int i = 0; i < 4; ++i) { v[i] = hist2[t * 4 + i]; sum += v[i]; }
    int pre = sum;
#pragma unroll
    for (int o = 1; o < 64; o <<= 1) {
      const int nb = __shfl_up(pre, o, 64);
      if (t >= o) pre += nb;
    }
    pre -= sum;
    int run = pre;
#pragma unroll
    for (int i = 0; i < 4; ++i) { exc[t * 4 + i] = run; run += v[i]; }
  }
  __syncthreads();
  const int node = b * 256 + t;
  if (node < NN) {
    cnt[node] = hist2[t];
    rowstart[node] = base + exc[t];
  }
  cur2[t] = exc[t];
  __syncthreads();
  for (int i = t; i < tot; i += 256) {
    const unsigned u = ebuf[i];
    const int p = atomicAdd(&cur2[u >> 17], 1);
    csrd[base + p] = (int)(u & 0x1ffffu);
  }
}

// ---------------- kernel 5: wave-per-node, lane owns 2 cols, 8 edges in flight ----
__global__ __launch_bounds__(256) void aggr_k(
    const unsigned short* __restrict__ h, const int* __restrict__ csrd,
    const int* __restrict__ rowstart, const int* __restrict__ cnt,
    const float* __restrict__ ssrc, const float* __restrict__ sdst,
    float* __restrict__ out) {
  const int lane = threadIdx.x & 63;
  const int node = blockIdx.x * 4 + (threadIdx.x >> 6);  // grid covers exactly NN
  const int r0 = rowstart[node];
  const int deg = cnt[node];
  const int jend = r0 + deg;
  const float sbase = ssrc[node];              // pre-scaled by log2(e)
  const unsigned* __restrict__ hp = (const unsigned*)h;  // 64 uints per row
  float a0 = 0.f, a1 = 0.f, sw = 0.f;
  const int nit = (deg + 7) >> 3;              // 8 edges per iteration, wave-wide row
  for (int it = 0; it < nit; ++it) {
    const int jb = r0 + it * 8;
    int d[8];
    unsigned pk[8];
    float w[8];
#pragma unroll
    for (int s = 0; s < 8; ++s) {
      const int jc = jb + s;
      const int jj = jc < jend ? jc : jend - 1;  // clamp (deg>0 inside loop)
      d[s] = csrd[jj];
    }
#pragma unroll
    for (int s = 0; s < 8; ++s)
      pk[s] = hp[(unsigned)d[s] * 64u + (unsigned)lane];  // 1 row per inst, coalesced
#pragma unroll
    for (int s = 0; s < 8; ++s) {
      const float sv = sbase + sdst[d[s]];       // broadcast gather
      float ww = exp2f(fmaxf(sv, 0.2f * sv));    // leaky+exp in log2 domain
      w[s] = (jb + s) < jend ? ww : 0.f;
      sw += w[s];
    }
#pragma unroll
    for (int s = 0; s < 8; ++s) {
      a0 = fmaf(w[s], bflo(pk[s]), a0);
      a1 = fmaf(w[s], bfhi(pk[s]), a1);
    }
  }
  const float inv = deg > 0 ? 1.0f / sw : 0.f;   // sw identical across lanes
  float o0 = a0 * inv, o1 = a1 * inv;
  o0 = o0 > 0.f ? o0 : __expf(o0) - 1.f;  // elu alpha=1
  o1 = o1 > 0.f ? o1 : __expf(o1) - 1.f;
  *(float2*)(out + (size_t)node * OD + lane * 2) = make_float2(o0, o1);
}

extern "C" void kernel_launch(void* const* d_in, const int* in_sizes, int n_in,
                              void* d_out, int out_size, void* d_ws, size_t ws_size,
                              hipStream_t stream) {
  const float* x = (const float*)d_in[0];
  const int* el = (const int*)d_in[1];
  const float* W = (const float*)d_in[2];
  const float* a = (const float*)d_in[3];
  float* out = (float*)d_out;
  char* ws = (char*)d_ws;

  const size_t S = 400384;  // 100000*4 padded to 512
  float* ssrc    = (float*)(ws + 0 * S);
  float* sdst    = (float*)(ws + 1 * S);
  int* cnt       = (int*)(ws + 2 * S);
  int* rowstart  = (int*)(ws + 3 * S);
  int* bcur      = (int*)(ws + 4 * S);          // 391 ints
  int* bbase     = (int*)(ws + 4 * S + 2048);   // 391 ints
  unsigned short* Wt = (unsigned short*)(ws + 4 * S + 8192);          // 64 KB
  unsigned short* h  = (unsigned short*)(ws + 4 * S + 8192 + 65536);  // 25.6 MB
  int* csrd = (int*)(ws + 4 * S + 8192 + 65536 + (size_t)NN * OD * 2);  // 6.4 MB
  // staging (12.81 MB) lives in d_out scratch space (51.2 MB); consumed by
  // place2_k before aggr_k rewrites every output element.
  unsigned* stage = (unsigned*)d_out;

  prep_wt_k<<<128, 256, 0, stream>>>(W, Wt, bcur);
  fused_k<<<NGB + NB, 512, 0, stream>>>(x, Wt, a, h, ssrc, sdst, el, bcur, stage);
  bscan_k<<<1, 512, 0, stream>>>(bcur, bbase);
  place2_k<<<NB, 256, 0, stream>>>(stage, bcur, bbase, csrd, cnt, rowstart);
  aggr_k<<<NN / 4, 256, 0, stream>>>(h, csrd, rowstart, cnt, ssrc, sdst, out);
}

// Round 7
// 122.123 us; speedup vs baseline: 3.7523x; 1.1250x over previous
//
#include <hip/hip_runtime.h>
#include <hip/hip_bf16.h>
#include <cstdint>
#include <cstddef>

#define NN 100000
#define NE 1600000
#define KD 256
#define OD 128
#define NB 391     // ceil(NN/256) buckets of 256 src nodes
#define CAP 8192   // staging capacity per bucket (mean 6250, sigma ~79)
#define NGB 782    // gemm blocks in fused kernel (128 rows each)

typedef __attribute__((ext_vector_type(8))) __bf16 bf16x8;
typedef __attribute__((ext_vector_type(4))) float f32x4;
typedef __attribute__((ext_vector_type(8))) unsigned short ushort8;

static __device__ __forceinline__ unsigned short f2bf(float f) {
  return __builtin_bit_cast(unsigned short, (__bf16)f);
}
static __device__ __forceinline__ float bflo(unsigned p) {
  return __builtin_bit_cast(float, p << 16);
}
static __device__ __forceinline__ float bfhi(unsigned p) {
  return __builtin_bit_cast(float, p & 0xffff0000u);
}

// ---------------- kernel 1: W -> Wt bf16 transposed; also init bcur ---------------
__global__ void prep_wt_k(const float* __restrict__ W, unsigned short* __restrict__ Wt,
                          int* __restrict__ bcur) {
  const int i = blockIdx.x * 256 + threadIdx.x;  // 32768 total
  const int k = i >> 7;   // 0..255
  const int n = i & 127;  // 0..127
  Wt[n * KD + k] = f2bf(W[i]);
  if (i < NB) bcur[i] = i * CAP;
}

// ---------------- kernel 2: FUSED  gemm (blocks 0..781) | bin (782..1172) ---------
// gemm: 8 waves, 128 rows/block, whole Wt in LDS (XOR-swizzled), MFMA 16x16x32.
// bin : 512 thr, 4096 edges/block, LDS bucket-sort by src>>8, append runs to stage.
__global__ __launch_bounds__(512, 4) void fused_k(
    const float* __restrict__ x, const unsigned short* __restrict__ Wt,
    const float* __restrict__ a, unsigned short* __restrict__ h,
    float* __restrict__ ssrc, float* __restrict__ sdst,
    const int* __restrict__ el, int* __restrict__ bcur,
    unsigned* __restrict__ stage) {
  __shared__ alignas(16) char smem[65536];
  const int t = threadIdx.x;

  if (blockIdx.x < NGB) {
    // ------------------------- GEMM part -------------------------
    unsigned short* Bl = (unsigned short*)smem;  // 128 rows x 512 B, swizzled
#pragma unroll
    for (int it = 0; it < 8; ++it) {
      const int c = it * 512 + t;        // 4096 chunks of 16 B
      const int r = c >> 5;
      const int c16 = c & 31;
      const ushort8 v = *(const ushort8*)(Wt + r * 256 + c16 * 8);
      const int byt = (r * 512 + c16 * 16) ^ ((r & 7) << 4);
      *(ushort8*)((char*)Bl + byt) = v;
    }
    const int lane = t & 63;
    const int wave = t >> 6;
    const int col = lane & 15;
    const int kg = lane >> 4;
    const int m0 = blockIdx.x * 128 + wave * 16;
    const int arow = m0 + col;
    const bool rowok = arow < NN;
    const float* __restrict__ xrow = x + (size_t)arow * KD;
    __syncthreads();

    f32x4 acc[8];
#pragma unroll
    for (int i = 0; i < 8; ++i) acc[i] = (f32x4)0.0f;

#pragma unroll
    for (int s = 0; s < 8; ++s) {
      const int kk = s * 32 + kg * 8;
      bf16x8 af = (bf16x8)(__bf16)0.0f;
      if (rowok) {
        const float4 f0 = *(const float4*)(xrow + kk);
        const float4 f1 = *(const float4*)(xrow + kk + 4);
        af[0] = (__bf16)f0.x; af[1] = (__bf16)f0.y; af[2] = (__bf16)f0.z; af[3] = (__bf16)f0.w;
        af[4] = (__bf16)f1.x; af[5] = (__bf16)f1.y; af[6] = (__bf16)f1.z; af[7] = (__bf16)f1.w;
      }
#pragma unroll
      for (int nt = 0; nt < 8; ++nt) {
        const int n = nt * 16 + col;
        const int byt = (n * 512 + s * 64 + kg * 16) ^ ((col & 7) << 4);
        const ushort8 bu = *(const ushort8*)((const char*)Bl + byt);
        const bf16x8 bf = __builtin_bit_cast(bf16x8, bu);
        acc[nt] = __builtin_amdgcn_mfma_f32_16x16x32_bf16(af, bf, acc[nt], 0, 0, 0);
      }
    }

    // C/D layout: col = lane&15, row = (lane>>4)*4 + r
    float ps[4] = {0.f, 0.f, 0.f, 0.f};
    float pd[4] = {0.f, 0.f, 0.f, 0.f};
#pragma unroll
    for (int nt = 0; nt < 8; ++nt) {
      const int n = nt * 16 + col;
      const float av = a[n];
      const float av2 = a[OD + n];
#pragma unroll
      for (int r = 0; r < 4; ++r) {
        const float v = acc[nt][r];
        const int row = m0 + kg * 4 + r;
        if (row < NN) h[(size_t)row * OD + n] = f2bf(v);
        ps[r] += v * av;
        pd[r] += v * av2;
      }
    }
#pragma unroll
    for (int off = 1; off < 16; off <<= 1) {
#pragma unroll
      for (int r = 0; r < 4; ++r) {
        ps[r] += __shfl_xor(ps[r], off, 64);
        pd[r] += __shfl_xor(pd[r], off, 64);
      }
    }
    if (col == 0) {
#pragma unroll
      for (int r = 0; r < 4; ++r) {
        const int row = m0 + kg * 4 + r;
        // pre-scale scores by log2(e): weight pass uses exp2 (leaky commutes w/ scale)
        if (row < NN) {
          ssrc[row] = ps[r] * 1.442695041f;
          sdst[row] = pd[r] * 1.442695041f;
        }
      }
    }
  } else {
    // ------------------------- BIN part -------------------------
    unsigned* sorted = (unsigned*)smem;                       // 16384 B
    unsigned short* bkid = (unsigned short*)(smem + 16384);   // 8192 B
    int* hist  = (int*)(smem + 24576);                        // 392*4
    int* off   = (int*)(smem + 26144);                        // 392*4
    int* cur   = (int*)(smem + 27712);                        // 391*4
    int* delta = (int*)(smem + 29276);                        // 391*4
    const int te = (blockIdx.x - NGB) * 4096 + t * 8;
    int s[8], d[8];
    bool valid[8];
#pragma unroll
    for (int u = 0; u < 8; ++u) valid[u] = (te + u) < NE;
    if (te + 7 < NE) {
      const int4 a0 = *(const int4*)(el + te);
      const int4 a1 = *(const int4*)(el + te + 4);
      const int4 b0 = *(const int4*)(el + NE + te);
      const int4 b1 = *(const int4*)(el + NE + te + 4);
      s[0] = a0.x; s[1] = a0.y; s[2] = a0.z; s[3] = a0.w;
      s[4] = a1.x; s[5] = a1.y; s[6] = a1.z; s[7] = a1.w;
      d[0] = b0.x; d[1] = b0.y; d[2] = b0.z; d[3] = b0.w;
      d[4] = b1.x; d[5] = b1.y; d[6] = b1.z; d[7] = b1.w;
    } else {
#pragma unroll
      for (int u = 0; u < 8; ++u) {
        s[u] = valid[u] ? el[te + u] : 0;
        d[u] = valid[u] ? el[NE + te + u] : 0;
      }
    }
    for (int i = t; i <= NB; i += 512) hist[i] = 0;
    __syncthreads();
#pragma unroll
    for (int u = 0; u < 8; ++u)
      if (valid[u]) atomicAdd(&hist[s[u] >> 8], 1);
    __syncthreads();
    // exclusive scan of hist[0..NB] by wave 0 (7 entries/lane)
    if (t < 64) {
      int v[7];
      int sum = 0;
#pragma unroll
      for (int i = 0; i < 7; ++i) {
        const int idx = t * 7 + i;
        v[i] = (idx <= NB) ? hist[idx] : 0;
        sum += v[i];
      }
      int pre = sum;
#pragma unroll
      for (int o = 1; o < 64; o <<= 1) {
        const int nb = __shfl_up(pre, o, 64);
        if (t >= o) pre += nb;
      }
      pre -= sum;  // exclusive across lanes
      int run = pre;
#pragma unroll
      for (int i = 0; i < 7; ++i) {
        const int idx = t * 7 + i;
        if (idx <= NB) off[idx] = run;
        run += v[i];
      }
    }
    __syncthreads();
    for (int i = t; i < NB; i += 512) cur[i] = off[i];
    __syncthreads();
#pragma unroll
    for (int u = 0; u < 8; ++u)
      if (valid[u]) {
        const int b = s[u] >> 8;
        const int p = atomicAdd(&cur[b], 1);
        sorted[p] = ((unsigned)(s[u] & 255) << 17) | (unsigned)d[u];
        bkid[p] = (unsigned short)b;
      }
    __syncthreads();
    for (int b = t; b < NB; b += 512) {
      const int len = off[b + 1] - off[b];
      if (len > 0) {
        const int gb = atomicAdd(&bcur[b], len);
        delta[b] = gb - off[b];
      }
    }
    __syncthreads();
    const int n = off[NB];
    for (int i = t; i < n; i += 512) {
      const int b = bkid[i];
      const int pos = delta[b] + i;
      if (pos < (b + 1) * CAP) stage[pos] = sorted[i];  // overflow clamp (never hit)
    }
  }
}

// ---------------- kernel 3: scan 391 bucket totals -> bucket CSR bases ------------
__global__ __launch_bounds__(512) void bscan_k(const int* __restrict__ bcur,
                                               int* __restrict__ bbase) {
  __shared__ int tmp[512];
  const int t = threadIdx.x;
  int v = 0;
  if (t < NB) {
    v = bcur[t] - t * CAP;
    v = v > CAP ? CAP : v;
  }
  tmp[t] = v;
  __syncthreads();
  for (int o = 1; o < 512; o <<= 1) {
    const int add = (t >= o) ? tmp[t - o] : 0;
    __syncthreads();
    tmp[t] += add;
    __syncthreads();
  }
  if (t < NB) bbase[t] = tmp[t] - v;  // exclusive
}

// ---------------- kernel 4: per-bucket LDS hist/scan + weight + place -------------
// Computes w = exp2(leaky(ssrc[s]+sdst[d])) per edge (scores pre-scaled by log2e),
// packs it as bf16-sans-sign (15 bits, w>0) with dst: entry = (w15<<17)|dst.
__global__ __launch_bounds__(256) void place2_k(const unsigned* __restrict__ stage,
                                                const int* __restrict__ bcur,
                                                const int* __restrict__ bbase,
                                                const float* __restrict__ ssrc,
                                                const float* __restrict__ sdst,
                                                unsigned* __restrict__ csrw,
                                                int* __restrict__ cnt,
                                                int* __restrict__ rowstart) {
  __shared__ unsigned ebuf[CAP];   // 32 KB
  __shared__ float sl[256];
  __shared__ int hist2[256];
  __shared__ int exc[256];
  __shared__ int cur2[256];
  const int b = blockIdx.x;
  const int t = threadIdx.x;
  int tot = bcur[b] - b * CAP;
  tot = tot > CAP ? CAP : tot;
  const int base = bbase[b];
  const int node = b * 256 + t;
  hist2[t] = 0;
  sl[t] = (node < NN) ? ssrc[node] : 0.f;
  for (int i = t; i < tot; i += 256) ebuf[i] = stage[(size_t)b * CAP + i];
  __syncthreads();
  for (int i = t; i < tot; i += 256) atomicAdd(&hist2[ebuf[i] >> 17], 1);
  __syncthreads();
  // exclusive scan of hist2[0..255] by wave 0 (4/lane)
  if (t < 64) {
    int v[4];
    int sum = 0;
#pragma unroll
    for (int i = 0; i < 4; ++i) { v[i] = hist2[t * 4 + i]; sum += v[i]; }
    int pre = sum;
#pragma unroll
    for (int o = 1; o < 64; o <<= 1) {
      const int nb = __shfl_up(pre, o, 64);
      if (t >= o) pre += nb;
    }
    pre -= sum;
    int run = pre;
#pragma unroll
    for (int i = 0; i < 4; ++i) { exc[t * 4 + i] = run; run += v[i]; }
  }
  __syncthreads();
  if (node < NN) {
    cnt[node] = hist2[t];
    rowstart[node] = base + exc[t];
  }
  cur2[t] = exc[t];
  __syncthreads();
  for (int i = t; i < tot; i += 256) {
    const unsigned u = ebuf[i];
    const int s = u >> 17;
    const unsigned d = u & 0x1ffffu;
    const float sv = sl[s] + sdst[d];                 // log2-domain score
    const float w = exp2f(fmaxf(sv, 0.2f * sv));      // leaky+exp, w > 0
    unsigned wb = __builtin_bit_cast(unsigned, w);
    wb += 0x7fffu + ((wb >> 16) & 1u);                // round-to-nearest bf16
    const unsigned ent = ((wb >> 16) << 17) | d;      // sign bit is 0 -> 15 bits
    const int p = atomicAdd(&cur2[s], 1);
    csrw[base + p] = ent;
  }
}

// ---------------- kernel 5: wave-per-node aggregate; weights pre-baked in CSR -----
// lane-group g = lane>>4 handles edge slot g; lane sub = lane&15 covers cols sub*8..+7
__global__ __launch_bounds__(256) void aggr_k(
    const unsigned short* __restrict__ h, const unsigned* __restrict__ csrw,
    const int* __restrict__ rowstart, const int* __restrict__ cnt,
    float* __restrict__ out) {
  const int lane = threadIdx.x & 63;
  const int g = lane >> 4;
  const int sub = lane & 15;
  const int node = blockIdx.x * 4 + (threadIdx.x >> 6);  // grid covers exactly NN
  const int r0 = rowstart[node];
  const int deg = cnt[node];
  const int jend = r0 + deg;
  const uint4* __restrict__ hp = (const uint4*)h;  // one h row = 16 uint4
  float acc[8] = {0.f, 0.f, 0.f, 0.f, 0.f, 0.f, 0.f, 0.f};
  float sw = 0.f;
  const int nit = (deg + 7) >> 3;  // 8 edges per iteration (4 groups x 2 slots)
  for (int it = 0; it < nit; ++it) {
    const int j0 = r0 + it * 8 + g;
    const int j1 = j0 + 4;
    const unsigned u0 = csrw[j0 < jend ? j0 : r0];
    const unsigned u1 = csrw[j1 < jend ? j1 : r0];
    const unsigned d0 = u0 & 0x1ffffu;
    const unsigned d1 = u1 & 0x1ffffu;
    const uint4 p0 = hp[d0 * 16u + sub];
    const uint4 p1 = hp[d1 * 16u + sub];
    const float w0 = (j0 < jend) ? __builtin_bit_cast(float, (u0 >> 17) << 16) : 0.f;
    const float w1 = (j1 < jend) ? __builtin_bit_cast(float, (u1 >> 17) << 16) : 0.f;
    sw += w0 + w1;
    const unsigned k0[4] = {p0.x, p0.y, p0.z, p0.w};
    const unsigned k1[4] = {p1.x, p1.y, p1.z, p1.w};
#pragma unroll
    for (int q = 0; q < 4; ++q) {
      acc[q * 2]     = fmaf(w0, bflo(k0[q]), fmaf(w1, bflo(k1[q]), acc[q * 2]));
      acc[q * 2 + 1] = fmaf(w0, bfhi(k0[q]), fmaf(w1, bfhi(k1[q]), acc[q * 2 + 1]));
    }
  }
  // reduce across the 4 edge-groups (same sub = same columns)
#pragma unroll
  for (int off = 16; off < 64; off <<= 1) {
    sw += __shfl_xor(sw, off, 64);
#pragma unroll
    for (int q = 0; q < 8; ++q) acc[q] += __shfl_xor(acc[q], off, 64);
  }
  const float inv = deg > 0 ? 1.0f / sw : 0.f;
  float o[8];
#pragma unroll
  for (int q = 0; q < 8; ++q) {
    const float v = acc[q] * inv;
    o[q] = v > 0.f ? v : __expf(v) - 1.f;  // elu alpha=1
  }
  if (lane < 16) {
    float4* op = (float4*)(out + (size_t)node * OD + sub * 8);
    op[0] = make_float4(o[0], o[1], o[2], o[3]);
    op[1] = make_float4(o[4], o[5], o[6], o[7]);
  }
}

extern "C" void kernel_launch(void* const* d_in, const int* in_sizes, int n_in,
                              void* d_out, int out_size, void* d_ws, size_t ws_size,
                              hipStream_t stream) {
  const float* x = (const float*)d_in[0];
  const int* el = (const int*)d_in[1];
  const float* W = (const float*)d_in[2];
  const float* a = (const float*)d_in[3];
  float* out = (float*)d_out;
  char* ws = (char*)d_ws;

  const size_t S = 400384;  // 100000*4 padded to 512
  float* ssrc    = (float*)(ws + 0 * S);
  float* sdst    = (float*)(ws + 1 * S);
  int* cnt       = (int*)(ws + 2 * S);
  int* rowstart  = (int*)(ws + 3 * S);
  int* bcur      = (int*)(ws + 4 * S);          // 391 ints
  int* bbase     = (int*)(ws + 4 * S + 2048);   // 391 ints
  unsigned short* Wt = (unsigned short*)(ws + 4 * S + 8192);          // 64 KB
  unsigned short* h  = (unsigned short*)(ws + 4 * S + 8192 + 65536);  // 25.6 MB
  unsigned* csrw = (unsigned*)(ws + 4 * S + 8192 + 65536 + (size_t)NN * OD * 2);  // 6.4 MB
  // staging (12.81 MB) lives in d_out scratch space (51.2 MB); consumed by
  // place2_k before aggr_k rewrites every output element.
  unsigned* stage = (unsigned*)d_out;

  prep_wt_k<<<128, 256, 0, stream>>>(W, Wt, bcur);
  fused_k<<<NGB + NB, 512, 0, stream>>>(x, Wt, a, h, ssrc, sdst, el, bcur, stage);
  bscan_k<<<1, 512, 0, stream>>>(bcur, bbase);
  place2_k<<<NB, 256, 0, stream>>>(stage, bcur, bbase, ssrc, sdst, csrw, cnt, rowstart);
  aggr_k<<<NN / 4, 256, 0, stream>>>(h, csrw, rowstart, cnt, out);
}

// Round 8
// 118.995 us; speedup vs baseline: 3.8509x; 1.0263x over previous
//
#include <hip/hip_runtime.h>
#include <hip/hip_bf16.h>
#include <cstdint>
#include <cstddef>

#define NN 100000
#define NE 1600000
#define KD 256
#define OD 128
#define NB 391     // ceil(NN/256) buckets of 256 src nodes
#define CAP 8192   // staging capacity per bucket (mean 6250, sigma ~79)
#define NGB 782    // gemm blocks in fused kernel (128 rows each)

typedef __attribute__((ext_vector_type(8))) __bf16 bf16x8;
typedef __attribute__((ext_vector_type(4))) float f32x4;
typedef __attribute__((ext_vector_type(8))) unsigned short ushort8;

static __device__ __forceinline__ unsigned short f2bf(float f) {
  return __builtin_bit_cast(unsigned short, (__bf16)f);
}
static __device__ __forceinline__ float bflo(unsigned p) {
  return __builtin_bit_cast(float, p << 16);
}
static __device__ __forceinline__ float bfhi(unsigned p) {
  return __builtin_bit_cast(float, p & 0xffff0000u);
}

// ---------------- kernel 1: W -> Wt bf16 transposed; also init bcur ---------------
__global__ void prep_wt_k(const float* __restrict__ W, unsigned short* __restrict__ Wt,
                          int* __restrict__ bcur) {
  const int i = blockIdx.x * 256 + threadIdx.x;  // 32768 total
  const int k = i >> 7;   // 0..255
  const int n = i & 127;  // 0..127
  Wt[n * KD + k] = f2bf(W[i]);
  if (i < NB) bcur[i] = i * CAP;
}

// ---------------- kernel 2: FUSED  gemm (blocks 0..781) | bin (782..1172) ---------
// gemm: 8 waves, 128 rows/block, whole Wt in LDS (XOR-swizzled), MFMA 16x16x32.
// bin : 512 thr, 4096 edges/block, LDS bucket-sort by src>>8, append runs to stage.
__global__ __launch_bounds__(512, 4) void fused_k(
    const float* __restrict__ x, const unsigned short* __restrict__ Wt,
    const float* __restrict__ a, unsigned short* __restrict__ h,
    float* __restrict__ ssrc, float* __restrict__ sdst,
    const int* __restrict__ el, int* __restrict__ bcur,
    unsigned* __restrict__ stage) {
  __shared__ alignas(16) char smem[65536];
  const int t = threadIdx.x;

  if (blockIdx.x < NGB) {
    // ------------------------- GEMM part -------------------------
    unsigned short* Bl = (unsigned short*)smem;  // 128 rows x 512 B, swizzled
#pragma unroll
    for (int it = 0; it < 8; ++it) {
      const int c = it * 512 + t;        // 4096 chunks of 16 B
      const int r = c >> 5;
      const int c16 = c & 31;
      const ushort8 v = *(const ushort8*)(Wt + r * 256 + c16 * 8);
      const int byt = (r * 512 + c16 * 16) ^ ((r & 7) << 4);
      *(ushort8*)((char*)Bl + byt) = v;
    }
    const int lane = t & 63;
    const int wave = t >> 6;
    const int col = lane & 15;
    const int kg = lane >> 4;
    const int m0 = blockIdx.x * 128 + wave * 16;
    const int arow = m0 + col;
    const bool rowok = arow < NN;
    const float* __restrict__ xrow = x + (size_t)arow * KD;
    __syncthreads();

    f32x4 acc[8];
#pragma unroll
    for (int i = 0; i < 8; ++i) acc[i] = (f32x4)0.0f;

#pragma unroll
    for (int s = 0; s < 8; ++s) {
      const int kk = s * 32 + kg * 8;
      bf16x8 af = (bf16x8)(__bf16)0.0f;
      if (rowok) {
        const float4 f0 = *(const float4*)(xrow + kk);
        const float4 f1 = *(const float4*)(xrow + kk + 4);
        af[0] = (__bf16)f0.x; af[1] = (__bf16)f0.y; af[2] = (__bf16)f0.z; af[3] = (__bf16)f0.w;
        af[4] = (__bf16)f1.x; af[5] = (__bf16)f1.y; af[6] = (__bf16)f1.z; af[7] = (__bf16)f1.w;
      }
#pragma unroll
      for (int nt = 0; nt < 8; ++nt) {
        const int n = nt * 16 + col;
        const int byt = (n * 512 + s * 64 + kg * 16) ^ ((col & 7) << 4);
        const ushort8 bu = *(const ushort8*)((const char*)Bl + byt);
        const bf16x8 bf = __builtin_bit_cast(bf16x8, bu);
        acc[nt] = __builtin_amdgcn_mfma_f32_16x16x32_bf16(af, bf, acc[nt], 0, 0, 0);
      }
    }

    // C/D layout: col = lane&15, row = (lane>>4)*4 + r
    float ps[4] = {0.f, 0.f, 0.f, 0.f};
    float pd[4] = {0.f, 0.f, 0.f, 0.f};
#pragma unroll
    for (int nt = 0; nt < 8; ++nt) {
      const int n = nt * 16 + col;
      const float av = a[n];
      const float av2 = a[OD + n];
#pragma unroll
      for (int r = 0; r < 4; ++r) {
        const float v = acc[nt][r];
        const int row = m0 + kg * 4 + r;
        if (row < NN) h[(size_t)row * OD + n] = f2bf(v);
        ps[r] += v * av;
        pd[r] += v * av2;
      }
    }
#pragma unroll
    for (int off = 1; off < 16; off <<= 1) {
#pragma unroll
      for (int r = 0; r < 4; ++r) {
        ps[r] += __shfl_xor(ps[r], off, 64);
        pd[r] += __shfl_xor(pd[r], off, 64);
      }
    }
    if (col == 0) {
#pragma unroll
      for (int r = 0; r < 4; ++r) {
        const int row = m0 + kg * 4 + r;
        // pre-scale scores by log2(e): weight pass uses exp2 (leaky commutes w/ scale)
        if (row < NN) {
          ssrc[row] = ps[r] * 1.442695041f;
          sdst[row] = pd[r] * 1.442695041f;
        }
      }
    }
  } else {
    // ------------------------- BIN part -------------------------
    unsigned* sorted = (unsigned*)smem;                       // 16384 B
    unsigned short* bkid = (unsigned short*)(smem + 16384);   // 8192 B
    int* hist  = (int*)(smem + 24576);                        // 392*4
    int* off   = (int*)(smem + 26144);                        // 392*4
    int* cur   = (int*)(smem + 27712);                        // 391*4
    int* delta = (int*)(smem + 29276);                        // 391*4
    const int te = (blockIdx.x - NGB) * 4096 + t * 8;
    int s[8], d[8];
    bool valid[8];
#pragma unroll
    for (int u = 0; u < 8; ++u) valid[u] = (te + u) < NE;
    if (te + 7 < NE) {
      const int4 a0 = *(const int4*)(el + te);
      const int4 a1 = *(const int4*)(el + te + 4);
      const int4 b0 = *(const int4*)(el + NE + te);
      const int4 b1 = *(const int4*)(el + NE + te + 4);
      s[0] = a0.x; s[1] = a0.y; s[2] = a0.z; s[3] = a0.w;
      s[4] = a1.x; s[5] = a1.y; s[6] = a1.z; s[7] = a1.w;
      d[0] = b0.x; d[1] = b0.y; d[2] = b0.z; d[3] = b0.w;
      d[4] = b1.x; d[5] = b1.y; d[6] = b1.z; d[7] = b1.w;
    } else {
#pragma unroll
      for (int u = 0; u < 8; ++u) {
        s[u] = valid[u] ? el[te + u] : 0;
        d[u] = valid[u] ? el[NE + te + u] : 0;
      }
    }
    for (int i = t; i <= NB; i += 512) hist[i] = 0;
    __syncthreads();
#pragma unroll
    for (int u = 0; u < 8; ++u)
      if (valid[u]) atomicAdd(&hist[s[u] >> 8], 1);
    __syncthreads();
    // exclusive scan of hist[0..NB] by wave 0 (7 entries/lane)
    if (t < 64) {
      int v[7];
      int sum = 0;
#pragma unroll
      for (int i = 0; i < 7; ++i) {
        const int idx = t * 7 + i;
        v[i] = (idx <= NB) ? hist[idx] : 0;
        sum += v[i];
      }
      int pre = sum;
#pragma unroll
      for (int o = 1; o < 64; o <<= 1) {
        const int nb = __shfl_up(pre, o, 64);
        if (t >= o) pre += nb;
      }
      pre -= sum;  // exclusive across lanes
      int run = pre;
#pragma unroll
      for (int i = 0; i < 7; ++i) {
        const int idx = t * 7 + i;
        if (idx <= NB) off[idx] = run;
        run += v[i];
      }
    }
    __syncthreads();
    for (int i = t; i < NB; i += 512) cur[i] = off[i];
    __syncthreads();
#pragma unroll
    for (int u = 0; u < 8; ++u)
      if (valid[u]) {
        const int b = s[u] >> 8;
        const int p = atomicAdd(&cur[b], 1);
        sorted[p] = ((unsigned)(s[u] & 255) << 17) | (unsigned)d[u];
        bkid[p] = (unsigned short)b;
      }
    __syncthreads();
    for (int b = t; b < NB; b += 512) {
      const int len = off[b + 1] - off[b];
      if (len > 0) {
        const int gb = atomicAdd(&bcur[b], len);
        delta[b] = gb - off[b];
      }
    }
    __syncthreads();
    const int n = off[NB];
    for (int i = t; i < n; i += 512) {
      const int b = bkid[i];
      const int pos = delta[b] + i;
      if (pos < (b + 1) * CAP) stage[pos] = sorted[i];  // overflow clamp (never hit)
    }
  }
}

// ---------------- kernel 3: per-bucket base-reduce + LDS hist/scan + weight + place
// Each block computes its own CSR base (reduce of clamped bucket counts < b), the
// per-node cnt/rowstart (packed uint2), and the weighted CSR:
// entry = (bf15(exp2(leaky(ssrc[s]+sdst[d])))<<17) | dst   (w>0 -> 15 bits suffice)
__global__ __launch_bounds__(256) void place2_k(const unsigned* __restrict__ stage,
                                                const int* __restrict__ bcur,
                                                const float* __restrict__ ssrc,
                                                const float* __restrict__ sdst,
                                                unsigned* __restrict__ csrw,
                                                uint2* __restrict__ rc) {
  __shared__ unsigned ebuf[CAP];   // 32 KB
  __shared__ float sl[256];
  __shared__ int hist2[256];
  __shared__ int exc[256];
  __shared__ int cur2[256];
  __shared__ int red[256];
  __shared__ int tot_s;
  const int b = blockIdx.x;
  const int t = threadIdx.x;
  const int node = b * 256 + t;
  // ---- in-block exclusive prefix over bucket totals (replaces bscan kernel) ----
  int partial = 0;
  for (int i = t; i < NB; i += 256) {
    int c = bcur[i] - i * CAP;
    c = c > CAP ? CAP : c;
    if (i == b) tot_s = c;
    if (i < b) partial += c;
  }
  red[t] = partial;
  hist2[t] = 0;
  sl[t] = (node < NN) ? ssrc[node] : 0.f;
  __syncthreads();
  for (int o = 128; o > 0; o >>= 1) {
    if (t < o) red[t] += red[t + o];
    __syncthreads();
  }
  const int base = red[0];
  const int tot = tot_s;
  for (int i = t; i < tot; i += 256) ebuf[i] = stage[(size_t)b * CAP + i];
  __syncthreads();
  for (int i = t; i < tot; i += 256) atomicAdd(&hist2[ebuf[i] >> 17], 1);
  __syncthreads();
  // exclusive scan of hist2[0..255] by wave 0 (4/lane)
  if (t < 64) {
    int v[4];
    int sum = 0;
#pragma unroll
    for (int i = 0; i < 4; ++i) { v[i] = hist2[t * 4 + i]; sum += v[i]; }
    int pre = sum;
#pragma unroll
    for (int o = 1; o < 64; o <<= 1) {
      const int nb = __shfl_up(pre, o, 64);
      if (t >= o) pre += nb;
    }
    pre -= sum;
    int run = pre;
#pragma unroll
    for (int i = 0; i < 4; ++i) { exc[t * 4 + i] = run; run += v[i]; }
  }
  __syncthreads();
  if (node < NN) rc[node] = make_uint2((unsigned)hist2[t], (unsigned)(base + exc[t]));
  cur2[t] = exc[t];
  __syncthreads();
  for (int i = t; i < tot; i += 256) {
    const unsigned u = ebuf[i];
    const int s = u >> 17;
    const unsigned d = u & 0x1ffffu;
    const float sv = sl[s] + sdst[d];                 // log2-domain score
    const float w = exp2f(fmaxf(sv, 0.2f * sv));      // leaky+exp, w > 0
    unsigned wb = __builtin_bit_cast(unsigned, w);
    wb += 0x7fffu + ((wb >> 16) & 1u);                // round-to-nearest bf16
    const unsigned ent = ((wb >> 16) << 17) | d;      // sign bit is 0 -> 15 bits
    const int p = atomicAdd(&cur2[s], 1);
    csrw[base + p] = ent;
  }
}

// ---------------- kernel 4: wave-per-node aggregate, 2-stage pipelined gathers ----
// lane-group g = lane>>4 handles edge slot g; lane sub = lane&15 covers cols sub*8..+7
__global__ __launch_bounds__(256) void aggr_k(
    const unsigned short* __restrict__ h, const unsigned* __restrict__ csrw,
    const uint2* __restrict__ rc, float* __restrict__ out) {
  const int lane = threadIdx.x & 63;
  const int g = lane >> 4;
  const int sub = lane & 15;
  const int node = blockIdx.x * 4 + (threadIdx.x >> 6);  // grid covers exactly NN
  const uint2 rcv = rc[node];
  const int deg = (int)rcv.x;
  const int r0 = (int)rcv.y;
  const int jend = r0 + deg;
  const uint4* __restrict__ hp = (const uint4*)h;  // one h row = 16 uint4
  float acc[8] = {0.f, 0.f, 0.f, 0.f, 0.f, 0.f, 0.f, 0.f};
  float sw = 0.f;
  const int nit = (deg + 7) >> 3;  // 8 edges per iteration (4 groups x 2 slots)
  if (nit > 0) {
    // prologue: stage A = iteration 0
    int j0 = r0 + g, j1 = j0 + 4;
    bool vA0 = j0 < jend, vA1 = j1 < jend;
    unsigned uA0 = csrw[vA0 ? j0 : r0];
    unsigned uA1 = csrw[vA1 ? j1 : r0];
    uint4 pA0 = hp[(uA0 & 0x1ffffu) * 16u + sub];
    uint4 pA1 = hp[(uA1 & 0x1ffffu) * 16u + sub];
    for (int it = 0; it < nit; ++it) {
      // issue stage B (iteration it+1) before consuming stage A
      unsigned uB0 = 0, uB1 = 0;
      uint4 pB0, pB1;
      bool vB0 = false, vB1 = false;
      if (it + 1 < nit) {
        const int k0 = r0 + (it + 1) * 8 + g;
        const int k1 = k0 + 4;
        vB0 = k0 < jend; vB1 = k1 < jend;
        uB0 = csrw[vB0 ? k0 : r0];
        uB1 = csrw[vB1 ? k1 : r0];
        pB0 = hp[(uB0 & 0x1ffffu) * 16u + sub];
        pB1 = hp[(uB1 & 0x1ffffu) * 16u + sub];
      }
      const float w0 = vA0 ? __builtin_bit_cast(float, (uA0 >> 17) << 16) : 0.f;
      const float w1 = vA1 ? __builtin_bit_cast(float, (uA1 >> 17) << 16) : 0.f;
      sw += w0 + w1;
      const unsigned k0a[4] = {pA0.x, pA0.y, pA0.z, pA0.w};
      const unsigned k1a[4] = {pA1.x, pA1.y, pA1.z, pA1.w};
#pragma unroll
      for (int q = 0; q < 4; ++q) {
        acc[q * 2]     = fmaf(w0, bflo(k0a[q]), fmaf(w1, bflo(k1a[q]), acc[q * 2]));
        acc[q * 2 + 1] = fmaf(w0, bfhi(k0a[q]), fmaf(w1, bfhi(k1a[q]), acc[q * 2 + 1]));
      }
      uA0 = uB0; uA1 = uB1; pA0 = pB0; pA1 = pB1; vA0 = vB0; vA1 = vB1;
    }
  }
  // reduce across the 4 edge-groups (same sub = same columns)
#pragma unroll
  for (int off = 16; off < 64; off <<= 1) {
    sw += __shfl_xor(sw, off, 64);
#pragma unroll
    for (int q = 0; q < 8; ++q) acc[q] += __shfl_xor(acc[q], off, 64);
  }
  const float inv = deg > 0 ? 1.0f / sw : 0.f;
  float o[8];
#pragma unroll
  for (int q = 0; q < 8; ++q) {
    const float v = acc[q] * inv;
    o[q] = v > 0.f ? v : __expf(v) - 1.f;  // elu alpha=1
  }
  if (lane < 16) {
    float4* op = (float4*)(out + (size_t)node * OD + sub * 8);
    op[0] = make_float4(o[0], o[1], o[2], o[3]);
    op[1] = make_float4(o[4], o[5], o[6], o[7]);
  }
}

extern "C" void kernel_launch(void* const* d_in, const int* in_sizes, int n_in,
                              void* d_out, int out_size, void* d_ws, size_t ws_size,
                              hipStream_t stream) {
  const float* x = (const float*)d_in[0];
  const int* el = (const int*)d_in[1];
  const float* W = (const float*)d_in[2];
  const float* a = (const float*)d_in[3];
  float* out = (float*)d_out;
  char* ws = (char*)d_ws;

  const size_t S = 400384;  // 100000*4 padded to 512
  float* ssrc    = (float*)(ws + 0 * S);
  float* sdst    = (float*)(ws + 1 * S);
  uint2* rc      = (uint2*)(ws + 2 * S);        // 800 KB (spans slots 2+3)
  int* bcur      = (int*)(ws + 4 * S);          // 391 ints
  unsigned short* Wt = (unsigned short*)(ws + 4 * S + 8192);          // 64 KB
  unsigned short* h  = (unsigned short*)(ws + 4 * S + 8192 + 65536);  // 25.6 MB
  unsigned* csrw = (unsigned*)(ws + 4 * S + 8192 + 65536 + (size_t)NN * OD * 2);  // 6.4 MB
  // staging (12.81 MB) lives in d_out scratch space (51.2 MB); consumed by
  // place2_k before aggr_k rewrites every output element.
  unsigned* stage = (unsigned*)d_out;

  prep_wt_k<<<128, 256, 0, stream>>>(W, Wt, bcur);
  fused_k<<<NGB + NB, 512, 0, stream>>>(x, Wt, a, h, ssrc, sdst, el, bcur, stage);
  place2_k<<<NB, 256, 0, stream>>>(stage, bcur, ssrc, sdst, csrw, rc);
  aggr_k<<<NN / 4, 256, 0, stream>>>(h, csrw, rc, out);
}